// Round 20
// baseline (333.188 us; speedup 1.0000x reference)
//
#include <hip/hip_runtime.h>
#include <float.h>

// ---------------------------------------------------------------------------
// SeqGraphRepNetwork. Round 20 = round 19 (best: 328.5us) + exp2 folding:
// log2(e) folded into qkv's q pre-scale (ASCALE = 1/sqrt(32)*log2e) so attn7
// uses exp2f directly -> drops the v_mul before every v_exp_f32 (40/tile on
// the serial softmax chain of the leading 55us kernel). Identical math
// modulo one rounding.
// ---------------------------------------------------------------------------

#define D 128
#define NHEAD 4
#define HD 32
#define MAXL 160
#define MAXNK 10     // max 16-key tiles (L<=160)
#define VP 168       // Vt / Pb key pitch in ushorts
#define WP 136       // LDS tile pitch in ushorts (272B)

typedef __attribute__((ext_vector_type(8))) short short8;
typedef __attribute__((ext_vector_type(4))) float floatx4;

// ---- bf16 <-> f32 helpers (raw ushort storage, RNE) ------------------------
__device__ __forceinline__ float lo2f(unsigned u) {
    union { unsigned i; float f; } x; x.i = u << 16; return x.f;
}
__device__ __forceinline__ float hi2f(unsigned u) {
    union { unsigned i; float f; } x; x.i = u & 0xffff0000u; return x.f;
}
__device__ __forceinline__ unsigned short f2bf(float f) {
    union { float f; unsigned i; } x; x.f = f;
    unsigned r = x.i + 0x7fffu + ((x.i >> 16) & 1u);
    return (unsigned short)(r >> 16);
}
__device__ __forceinline__ unsigned pack2(float a, float b) {
    return (unsigned)f2bf(a) | ((unsigned)f2bf(b) << 16);
}
__device__ __forceinline__ float bf2f(unsigned short u) {
    union { unsigned i; float f; } x; x.i = (unsigned)u << 16; return x.f;
}

// ---- prep1: c_src/c_dst = a@att_W; u,z refold vectors (1 block, 128 thr) ---
__global__ void prep1(const float* __restrict__ att_W, const float* __restrict__ a_src,
                      const float* __restrict__ a_dst, const float* __restrict__ in_proj_w,
                      const float* __restrict__ in_proj_b, const float* __restrict__ g1,
                      const float* __restrict__ b1, float* __restrict__ c_src,
                      float* __restrict__ c_dst, float* __restrict__ u, float* __restrict__ z) {
    int p = threadIdx.x;  // 128
    float s = 0.f, d = 0.f, su = 0.f, sz = 0.f;
    for (int q = 0; q < D; q++) {
        float w = att_W[q * D + p];
        s += a_src[q] * w;
        d += a_dst[q] * w;
        float wq = in_proj_w[p * D + q];
        su += g1[q] * wq;
        sz += b1[q] * wq;
    }
    c_src[p] = s;
    c_dst[p] = d;
    u[p] = su;
    z[p] = sz + in_proj_b[p];
}

// ---- prep2: blocks 0..127 -> tb (4 buckets each); 128..511 -> bf16 weights -
// wb slots: 0 = W'q (Wq*g1), 1 = Wk, 2 = Wv, 3 = Wo, 4 = W1, 5 = W2.
__global__ void prep2(const float* __restrict__ delta, const float* __restrict__ c_src,
                      const float* __restrict__ in_proj_w, const float* __restrict__ out_proj_w,
                      const float* __restrict__ ffn_w1, const float* __restrict__ ffn_w2,
                      const float* __restrict__ ln1_g, float* __restrict__ tb,
                      unsigned short* __restrict__ wb) {
    int blk = blockIdx.x, t = threadIdx.x;
    if (blk < 128) {
        int b = blk * 4 + (t >> 6);
        int l = t & 63;
        const float* row = delta + (size_t)b * D;
        float s = row[l] * c_src[l] + row[l + 64] * c_src[l + 64];
        #pragma unroll
        for (int o = 32; o; o >>= 1) s += __shfl_down(s, o, 64);
        if (l == 0) tb[b] = s;
    } else {
        int idx = (blk - 128) * 256 + t;   // 384*256 = 98304 = 6*128*128
        int m = idx >> 14;
        int within = idx & (D * D - 1);
        float v;
        if (m == 0) v = in_proj_w[within] * ln1_g[within & (D - 1)];
        else if (m == 1) v = in_proj_w[D * D + within];
        else if (m == 2) v = in_proj_w[2 * D * D + within];
        else if (m == 3) v = out_proj_w[within];
        else if (m == 4) v = ffn_w1[within];
        else v = ffn_w2[within];
        wb[idx] = f2bf(v);
    }
}

// ---- gather_hu: block = 8 nodes + 2-row halo; HALF-WAVE per row. -----------
__launch_bounds__(256)
__global__ void gather_hu(const float* __restrict__ POI, const int* __restrict__ sess_idx,
                          const int* __restrict__ node_pos, const int* __restrict__ batch_ids,
                          const int* __restrict__ edge_dist, const int* __restrict__ lengths,
                          const float* __restrict__ c_src, const float* __restrict__ c_dst,
                          const float* __restrict__ tb, unsigned short* __restrict__ Hu,
                          float* __restrict__ muv, float* __restrict__ rinvv,
                          int* __restrict__ starts, int N) {
    __shared__ unsigned xs[10 * 64];      // 2.5 KB packed bf16x2
    __shared__ float s1s[10], s2s[10];
    int R0 = blockIdx.x * 8;
    int t = threadIdx.x;
    int hw = t >> 5, l32 = t & 31;        // 8 half-waves, 32 lanes each
    float4 cs4 = *(const float4*)(c_src + l32 * 4);
    float4 cd4 = *(const float4*)(c_dst + l32 * 4);
    #pragma unroll
    for (int i = hw; i < 10; i += 8) {
        int n = R0 - 1 + i;
        if (n >= 0 && n < N) {
            int row = sess_idx[n];
            float4 v = *(const float4*)(POI + (size_t)row * D + l32 * 4);
            ((uint2*)(xs + i * 64))[l32] = make_uint2(pack2(v.x, v.y), pack2(v.z, v.w));
            if (i >= 1 && i <= 8) {        // halo dots are never used
                float ps = v.x * cs4.x + v.y * cs4.y + v.z * cs4.z + v.w * cs4.w;
                float pd = v.x * cd4.x + v.y * cd4.y + v.z * cd4.z + v.w * cd4.w;
                #pragma unroll
                for (int o = 16; o; o >>= 1) {   // stays within the 32-half
                    ps += __shfl_down(ps, o, 64);
                    pd += __shfl_down(pd, o, 64);
                }
                if (l32 == 0) { s1s[i] = ps; s2s[i] = pd; }
            }
        }
    }
    __syncthreads();
    int j = hw;                            // one node per half-wave
    int n = R0 + j;
    if (n >= N) return;
    int g = batch_ids[n], pos = node_pos[n], L = lengths[g];
    bool hasF = pos > 0;
    bool hasB = pos < L - 1;
    float la = hasF ? (s1s[j + 1] + tb[edge_dist[n - 1 - g]]) : -FLT_MAX;
    float lb = hasB ? s2s[j + 1] : -FLT_MAX;
    float m = fmaxf(la, lb);
    float ea = hasF ? __expf(la - m) : 0.f;
    float eb = hasB ? __expf(lb - m) : 0.f;
    float inv = 1.f / (ea + eb + 1e-16f);
    float wa = ea * inv, wb = eb * inv;
    uint2 a = hasF ? ((const uint2*)(xs + j * 64))[l32] : make_uint2(0u, 0u);
    uint2 b = hasB ? ((const uint2*)(xs + (j + 2) * 64))[l32] : make_uint2(0u, 0u);
    float h0 = wa * lo2f(a.x) + wb * lo2f(b.x);
    float h1 = wa * hi2f(a.x) + wb * hi2f(b.x);
    float h2 = wa * lo2f(a.y) + wb * lo2f(b.y);
    float h3 = wa * hi2f(a.y) + wb * hi2f(b.y);
    ((uint2*)Hu)[(size_t)n * 32 + l32] = make_uint2(pack2(h0, h1), pack2(h2, h3));
    float s = h0 + h1 + h2 + h3;
    float ss = h0 * h0 + h1 * h1 + h2 * h2 + h3 * h3;
    #pragma unroll
    for (int o = 1; o < 32; o <<= 1) {     // xor <=16 stays within the half
        s += __shfl_xor(s, o, 64);
        ss += __shfl_xor(ss, o, 64);
    }
    if (l32 == 0) {
        float mu = s * (1.f / D);
        float var = ss * (1.f / D) - mu * mu;
        muv[n] = mu;
        rinvv[n] = rsqrtf(var + 1e-8f);
        if (pos == 0) starts[g] = n;
    }
}

// ---- qkv_split: grid (gb, 3); blockIdx.y = pass (0=k, 1=v, 2=q refold). ----
__launch_bounds__(256)
__global__ void qkv_split(const unsigned short* __restrict__ Hu, const unsigned short* __restrict__ wb,
                          const float* __restrict__ in_proj_b, const float* __restrict__ u,
                          const float* __restrict__ z, const float* __restrict__ muv,
                          const float* __restrict__ rinvv,
                          unsigned short* __restrict__ qo, unsigned short* __restrict__ ko,
                          unsigned short* __restrict__ vT, int M, int Npad) {
    __shared__ unsigned short Wl[128 * WP];
    int t = threadIdx.x;
    int wv = t >> 6, lane = t & 63;
    int quad = lane >> 4, l16 = lane & 15;
    int r0 = blockIdx.x * 128;
    int rbase = r0 + wv * 32;
    int p = blockIdx.y;
    // 1/sqrt(32) * log2(e): attn uses exp2 directly (saves a v_mul per exp)
    const float ASCALE = 0.25504364148122793f;
    const unsigned short* W = wb + (p == 0 ? 1 : p == 1 ? 2 : 0) * (D * D);
    for (int i = t; i < 2048; i += 256) {
        int c = i >> 4, kc = (i & 15) * 8;
        *(uint4*)&Wl[c * WP + kc] = *(const uint4*)(W + c * 128 + kc);
    }
    short8 af[2][4];
    #pragma unroll
    for (int mt = 0; mt < 2; mt++) {
        int r = rbase + mt * 16 + l16;
        #pragma unroll
        for (int kk = 0; kk < 4; kk++) {
            if (r < M) af[mt][kk] = *(const short8*)(Hu + (size_t)r * D + kk * 32 + quad * 8);
            else af[mt][kk] = (short8){0, 0, 0, 0, 0, 0, 0, 0};
        }
    }
    __syncthreads();
    floatx4 acc[2][8];
    #pragma unroll
    for (int i = 0; i < 2; i++)
        #pragma unroll
        for (int j = 0; j < 8; j++) acc[i][j] = (floatx4){0.f, 0.f, 0.f, 0.f};
    #pragma unroll
    for (int kk = 0; kk < 4; kk++)
        #pragma unroll
        for (int nt = 0; nt < 8; nt++) {
            short8 bf = *(const short8*)&Wl[(nt * 16 + l16) * WP + kk * 32 + quad * 8];
            acc[0][nt] = __builtin_amdgcn_mfma_f32_16x16x32_bf16(af[0][kk], bf, acc[0][nt], 0, 0, 0);
            acc[1][nt] = __builtin_amdgcn_mfma_f32_16x16x32_bf16(af[1][kk], bf, acc[1][nt], 0, 0, 0);
        }
    __syncthreads();   // all waves done reading Wl weights
    if (p == 1) {          // vT tile: Wl[col][localnode]
        #pragma unroll
        for (int nt = 0; nt < 8; nt++) {
            int col = nt * 16 + l16;
            float bv = in_proj_b[2 * D + col];
            #pragma unroll
            for (int mt = 0; mt < 2; mt++)
                #pragma unroll
                for (int r = 0; r < 4; r++) {
                    int ln = wv * 32 + mt * 16 + quad * 4 + r;
                    Wl[col * WP + ln] = (r0 + ln < M) ? f2bf(acc[mt][nt][r] + bv)
                                                      : (unsigned short)0;
                }
        }
    } else if (p == 0) {   // k tile: Wl[localrow][col]
        #pragma unroll
        for (int nt = 0; nt < 8; nt++) {
            int col = nt * 16 + l16;
            float bv = in_proj_b[D + col];
            #pragma unroll
            for (int mt = 0; mt < 2; mt++)
                #pragma unroll
                for (int r = 0; r < 4; r++)
                    Wl[(wv * 32 + mt * 16 + quad * 4 + r) * WP + col] =
                        f2bf(acc[mt][nt][r] + bv);
        }
    } else {               // q refold tile, pre-scaled by 1/sqrt(32)*log2e
        float uc[8], zc[8];
        #pragma unroll
        for (int nt = 0; nt < 8; nt++) {
            uc[nt] = u[nt * 16 + l16];
            zc[nt] = z[nt * 16 + l16] * ASCALE;
        }
        #pragma unroll
        for (int mt = 0; mt < 2; mt++)
            #pragma unroll
            for (int r = 0; r < 4; r++) {
                int ln = wv * 32 + mt * 16 + quad * 4 + r;
                int grow = r0 + ln;
                float mr = grow < M ? muv[grow] : 0.f;
                float rr = (grow < M ? rinvv[grow] : 0.f) * ASCALE;
                #pragma unroll
                for (int nt = 0; nt < 8; nt++)
                    Wl[ln * WP + nt * 16 + l16] =
                        f2bf(rr * (acc[mt][nt][r] - mr * uc[nt]) + zc[nt]);
            }
    }
    __syncthreads();
    if (p == 1) {
        for (int i = t; i < 2048; i += 256) {
            int col = i >> 4, c8 = (i & 15) * 8;
            *(uint4*)(vT + (size_t)col * Npad + r0 + c8) = *(uint4*)&Wl[col * WP + c8];
        }
    } else {
        unsigned short* out = (p == 0) ? ko : qo;
        for (int i = t; i < 2048; i += 256) {
            int row = i >> 4, c8 = (i & 15) * 8;
            if (r0 + row < M)
                *(uint4*)(out + (size_t)(r0 + row) * D + c8) = *(uint4*)&Wl[row * WP + c8];
        }
    }
}

// ---- attn8: 2 waves; LPT remap; q prefetch; no max-pass; exp2 (log2e folded
// into q); 1/l folded into O.
__launch_bounds__(128)
__global__ void attn8(const unsigned short* __restrict__ qb,
                      const unsigned short* __restrict__ kb,
                      const unsigned short* __restrict__ vT,
                      const int* __restrict__ starts, const int* __restrict__ lengths,
                      unsigned short* __restrict__ ctx, int Npad) {
    __shared__ unsigned short Vt[HD * VP];       // 10.5 KB [dim][key]
    __shared__ unsigned short Pb[2 * 16 * VP];   // 10.5 KB, per-wave halves
    int g = blockIdx.x;
    if (gridDim.x == 1024) {
        int bid = blockIdx.x;
        if (bid < 430) { int r = 96 - bid / 10; g = r + 97 * (bid % 10); }
        else { int b2 = bid - 430; int r = 53 - b2 / 11; g = r + 97 * (b2 % 11); }
    }
    int h = blockIdx.y;
    int start = starts[g], L = lengths[g];
    int t = threadIdx.x;
    int wv = t >> 6, lane = t & 63;
    int l16 = lane & 15, quad = lane >> 4;
    int nk = (L + 15) >> 4;
    int nk2 = (L + 31) >> 5;
    for (int i = t; i < 16 * VP; i += 128) ((unsigned*)Pb)[i] = 0u;
    int nch = nk2 * 4;
    for (int i = t; i < HD * nch; i += 128) {
        int r = i / nch, c = i - r * nch;
        *(uint4*)&Vt[r * VP + c * 8] =
            *(const uint4*)(vT + (size_t)(h * HD + r) * Npad + start + c * 8);
    }
    short8 kf[MAXNK];
    #pragma unroll
    for (int kt = 0; kt < MAXNK; kt++) {
        kf[kt] = (short8){0, 0, 0, 0, 0, 0, 0, 0};
        if (kt < nk) {
            int r = kt * 16 + l16;
            if (r < L) kf[kt] = *(const short8*)(kb + (size_t)(start + r) * D + h * HD + quad * 8);
        }
    }
    short8 qf[5];
    #pragma unroll
    for (int i = 0; i < 5; i++) {
        qf[i] = (short8){0, 0, 0, 0, 0, 0, 0, 0};
        int qt = wv + 2 * i;
        if (qt < nk) {
            int qrow = qt * 16 + l16;
            if (qrow < L)
                qf[i] = *(const short8*)(qb + (size_t)(start + qrow) * D + h * HD + quad * 8);
        }
    }
    __syncthreads();
    unsigned short* Pw = Pb + wv * 16 * VP;
    #pragma unroll
    for (int i = 0; i < 5; i++) {
        int qt = wv + 2 * i;
        if (qt >= nk) break;
        int q0 = qt * 16;
        floatx4 sacc[MAXNK];
        #pragma unroll
        for (int kt = 0; kt < MAXNK; kt++)
            if (kt < nk)
                sacc[kt] = __builtin_amdgcn_mfma_f32_16x16x32_bf16(
                    kf[kt], qf[i], (floatx4){0.f, 0.f, 0.f, 0.f}, 0, 0, 0);
        float lsum = 0.f;
        #pragma unroll
        for (int kt = 0; kt < MAXNK; kt++)
            if (kt < nk) {
                #pragma unroll
                for (int r = 0; r < 4; r++) {
                    int key = kt * 16 + quad * 4 + r;
                    float p = (key < L) ? exp2f(sacc[kt][r]) : 0.f;  // log2e pre-folded
                    sacc[kt][r] = p;
                    lsum += p;
                }
            }
        #pragma unroll
        for (int kt = 0; kt < MAXNK; kt++)
            if (kt < nk) {
                *(unsigned*)&Pw[l16 * VP + kt * 16 + quad * 4] =
                    pack2(sacc[kt][0], sacc[kt][1]);
                *(unsigned*)&Pw[l16 * VP + kt * 16 + quad * 4 + 2] =
                    pack2(sacc[kt][2], sacc[kt][3]);
            }
        lsum += __shfl_xor(lsum, 16);
        lsum += __shfl_xor(lsum, 32);
        float inv = 1.f / lsum;
        #pragma unroll
        for (int nc = 0; nc < 2; nc++) {
            floatx4 oacc = (floatx4){0.f, 0.f, 0.f, 0.f};
            #pragma unroll
            for (int kc = 0; kc < 5; kc++)
                if (kc < nk2) {
                    short8 pf = *(const short8*)&Pw[l16 * VP + kc * 32 + quad * 8];
                    short8 vf = *(const short8*)&Vt[(nc * 16 + l16) * VP + kc * 32 + quad * 8];
                    oacc = __builtin_amdgcn_mfma_f32_16x16x32_bf16(pf, vf, oacc, 0, 0, 0);
                }
            #pragma unroll
            for (int r = 0; r < 4; r++) {
                int qr = q0 + quad * 4 + r;
                if (qr < L)
                    ctx[(size_t)(start + qr) * D + h * HD + nc * 16 + l16] =
                        f2bf(oacc[r] * inv);
            }
        }
    }
}

// ---- outproj_ln2: out2 = LN2( ctx@Wo^T + bo + Q ), Q from Hu (LDS-staged) --
__launch_bounds__(256)
__global__ void outproj_ln2(const unsigned short* __restrict__ ctx, const unsigned short* __restrict__ W,
                            const float* __restrict__ bo, const unsigned short* __restrict__ Hu,
                            const float* __restrict__ muv, const float* __restrict__ rinvv,
                            const float* __restrict__ g1, const float* __restrict__ b1,
                            const float* __restrict__ g2, const float* __restrict__ b2,
                            unsigned short* __restrict__ out, int M) {
    __shared__ unsigned short Wl[128 * WP];
    int t = threadIdx.x;
    int wv = t >> 6, lane = t & 63;
    int quad = lane >> 4, l16 = lane & 15;
    int r0 = blockIdx.x * 128;
    int rbase = r0 + wv * 32;
    for (int i = t; i < 2048; i += 256) {
        int c = i >> 4, kc = (i & 15) * 8;
        *(uint4*)&Wl[c * WP + kc] = *(const uint4*)(W + c * 128 + kc);
    }
    __syncthreads();
    floatx4 acc[2][8];
    #pragma unroll
    for (int i = 0; i < 2; i++)
        #pragma unroll
        for (int j = 0; j < 8; j++) acc[i][j] = (floatx4){0.f, 0.f, 0.f, 0.f};
    #pragma unroll
    for (int kk = 0; kk < 4; kk++) {
        short8 af[2];
        #pragma unroll
        for (int mt = 0; mt < 2; mt++) {
            int r = rbase + mt * 16 + l16;
            if (r < M) af[mt] = *(const short8*)(ctx + (size_t)r * D + kk * 32 + quad * 8);
            else af[mt] = (short8){0, 0, 0, 0, 0, 0, 0, 0};
        }
        #pragma unroll
        for (int nt = 0; nt < 8; nt++) {
            short8 bf = *(const short8*)&Wl[(nt * 16 + l16) * WP + kk * 32 + quad * 8];
            acc[0][nt] = __builtin_amdgcn_mfma_f32_16x16x32_bf16(af[0], bf, acc[0][nt], 0, 0, 0);
            acc[1][nt] = __builtin_amdgcn_mfma_f32_16x16x32_bf16(af[1], bf, acc[1][nt], 0, 0, 0);
        }
    }
    __syncthreads();   // done reading Wo
    for (int i = t; i < 2048; i += 256) {
        int row = i >> 4, c8 = (i & 15) * 8;
        uint4 hv = make_uint4(0u, 0u, 0u, 0u);
        if (r0 + row < M) hv = *(const uint4*)(Hu + (size_t)(r0 + row) * D + c8);
        *(uint4*)&Wl[row * WP + c8] = hv;
    }
    __syncthreads();
    float g1c[8], b1c[8], boc[8], g2c[8], b2c[8];
    #pragma unroll
    for (int nt = 0; nt < 8; nt++) {
        int col = nt * 16 + l16;
        g1c[nt] = g1[col]; b1c[nt] = b1[col]; boc[nt] = bo[col];
        g2c[nt] = g2[col]; b2c[nt] = b2[col];
    }
    #pragma unroll
    for (int mt = 0; mt < 2; mt++) {
        #pragma unroll
        for (int r = 0; r < 4; r++) {
            int lrow = wv * 32 + mt * 16 + quad * 4 + r;
            int grow = r0 + lrow;
            bool ok = grow < M;
            float mr = ok ? muv[grow] : 0.f;
            float rr = ok ? rinvv[grow] : 0.f;
            float vv[8];
            float s = 0.f, ss = 0.f;
            #pragma unroll
            for (int nt = 0; nt < 8; nt++) {
                float huv = bf2f(Wl[lrow * WP + nt * 16 + l16]);
                float qv = (huv - mr) * rr * g1c[nt] + b1c[nt];
                float v = acc[mt][nt][r] + boc[nt] + qv;
                vv[nt] = v;
                s += v; ss += v * v;
            }
            #pragma unroll
            for (int o = 1; o < 16; o <<= 1) {
                s += __shfl_xor(s, o, 64);
                ss += __shfl_xor(ss, o, 64);
            }
            float mu = s * (1.f / D);
            float var = ss * (1.f / D) - mu * mu;
            float rinv = rsqrtf(var + 1e-8f);
            #pragma unroll
            for (int nt = 0; nt < 8; nt++)
                Wl[lrow * WP + nt * 16 + l16] =
                    f2bf((vv[nt] - mu) * rinv * g2c[nt] + b2c[nt]);
        }
    }
    __syncthreads();
    for (int i = t; i < 2048; i += 256) {
        int row = i >> 4, c8 = (i & 15) * 8;
        if (r0 + row < M)
            *(uint4*)(out + (size_t)(r0 + row) * D + c8) = *(uint4*)&Wl[row * WP + c8];
    }
}

// ---- ffn_fused: fin = out2 + relu(out2@W1^T+b1)@W2^T + b2 ------------------
__launch_bounds__(256)
__global__ void ffn_fused(const unsigned short* __restrict__ out2, const unsigned short* __restrict__ W1,
                          const float* __restrict__ b1f, const unsigned short* __restrict__ W2,
                          const float* __restrict__ b2f, unsigned short* __restrict__ fin, int M) {
    __shared__ unsigned short Wl[128 * WP];
    int t = threadIdx.x;
    int wv = t >> 6, lane = t & 63;
    int quad = lane >> 4, l16 = lane & 15;
    int r0 = blockIdx.x * 128;
    int rbase = r0 + wv * 32;
    int lbase = wv * 32;
    for (int i = t; i < 2048; i += 256) {    // stage W1
        int c = i >> 4, kc = (i & 15) * 8;
        *(uint4*)&Wl[c * WP + kc] = *(const uint4*)(W1 + c * 128 + kc);
    }
    short8 af[2][4];
    #pragma unroll
    for (int mt = 0; mt < 2; mt++) {
        int r = rbase + mt * 16 + l16;
        #pragma unroll
        for (int kk = 0; kk < 4; kk++) {
            if (r < M) af[mt][kk] = *(const short8*)(out2 + (size_t)r * D + kk * 32 + quad * 8);
            else af[mt][kk] = (short8){0, 0, 0, 0, 0, 0, 0, 0};
        }
    }
    __syncthreads();
    floatx4 acc[2][8];
    #pragma unroll
    for (int i = 0; i < 2; i++)
        #pragma unroll
        for (int j = 0; j < 8; j++) acc[i][j] = (floatx4){0.f, 0.f, 0.f, 0.f};
    #pragma unroll
    for (int kk = 0; kk < 4; kk++)
        #pragma unroll
        for (int nt = 0; nt < 8; nt++) {
            short8 bf = *(const short8*)&Wl[(nt * 16 + l16) * WP + kk * 32 + quad * 8];
            acc[0][nt] = __builtin_amdgcn_mfma_f32_16x16x32_bf16(af[0][kk], bf, acc[0][nt], 0, 0, 0);
            acc[1][nt] = __builtin_amdgcn_mfma_f32_16x16x32_bf16(af[1][kk], bf, acc[1][nt], 0, 0, 0);
        }
    __syncthreads();   // done reading W1
    #pragma unroll
    for (int nt = 0; nt < 8; nt++) {
        int col = nt * 16 + l16;
        float bv = b1f[col];
        #pragma unroll
        for (int mt = 0; mt < 2; mt++)
            #pragma unroll
            for (int r = 0; r < 4; r++)
                Wl[(lbase + mt * 16 + quad * 4 + r) * WP + col] =
                    f2bf(fmaxf(acc[mt][nt][r] + bv, 0.f));
    }
    __syncthreads();
    short8 af2[2][4];
    #pragma unroll
    for (int mt = 0; mt < 2; mt++)
        #pragma unroll
        for (int kk = 0; kk < 4; kk++)
            af2[mt][kk] = *(const short8*)&Wl[(lbase + mt * 16 + l16) * WP + kk * 32 + quad * 8];
    __syncthreads();
    for (int i = t; i < 2048; i += 256) {    // stage W2
        int c = i >> 4, kc = (i & 15) * 8;
        *(uint4*)&Wl[c * WP + kc] = *(const uint4*)(W2 + c * 128 + kc);
    }
    __syncthreads();
    #pragma unroll
    for (int i = 0; i < 2; i++)
        #pragma unroll
        for (int j = 0; j < 8; j++) acc[i][j] = (floatx4){0.f, 0.f, 0.f, 0.f};
    #pragma unroll
    for (int kk = 0; kk < 4; kk++)
        #pragma unroll
        for (int nt = 0; nt < 8; nt++) {
            short8 bf = *(const short8*)&Wl[(nt * 16 + l16) * WP + kk * 32 + quad * 8];
            acc[0][nt] = __builtin_amdgcn_mfma_f32_16x16x32_bf16(af2[0][kk], bf, acc[0][nt], 0, 0, 0);
            acc[1][nt] = __builtin_amdgcn_mfma_f32_16x16x32_bf16(af2[1][kk], bf, acc[1][nt], 0, 0, 0);
        }
    __syncthreads();   // done reading W2
    #pragma unroll
    for (int nt = 0; nt < 8; nt++) {
        int col = nt * 16 + l16;
        float bv = b2f[col];
        #pragma unroll
        for (int mt = 0; mt < 2; mt++)
            #pragma unroll
            for (int r = 0; r < 4; r++)
                Wl[(lbase + mt * 16 + quad * 4 + r) * WP + col] = f2bf(acc[mt][nt][r] + bv);
    }
    __syncthreads();
    for (int i = t; i < 2048; i += 256) {
        int row = i >> 4, c8 = (i & 15) * 8;
        int grow = r0 + row;
        if (grow < M) {
            uint4 a = *(uint4*)&Wl[row * WP + c8];
            uint4 b = *(const uint4*)(out2 + (size_t)grow * D + c8);
            uint4 o;
            o.x = pack2(lo2f(a.x) + lo2f(b.x), hi2f(a.x) + hi2f(b.x));
            o.y = pack2(lo2f(a.y) + lo2f(b.y), hi2f(a.y) + hi2f(b.y));
            o.z = pack2(lo2f(a.z) + lo2f(b.z), hi2f(a.z) + hi2f(b.z));
            o.w = pack2(lo2f(a.w) + lo2f(b.w), hi2f(a.w) + hi2f(b.w));
            *(uint4*)(fin + (size_t)grow * D + c8) = o;
        }
    }
}

// ---- masked mean pool (bf16 -> fp32 out) -----------------------------------
__global__ void pool_k(const unsigned short* __restrict__ fin, const int* __restrict__ starts,
                       const int* __restrict__ lengths, float* __restrict__ out) {
    int g = blockIdx.x, d = threadIdx.x;  // 128 threads
    int start = starts[g], L = lengths[g];
    float s0 = 0.f, s1 = 0.f, s2 = 0.f, s3 = 0.f;
    int p = 0;
    for (; p + 4 <= L; p += 4) {
        s0 += bf2f(fin[(size_t)(start + p) * D + d]);
        s1 += bf2f(fin[(size_t)(start + p + 1) * D + d]);
        s2 += bf2f(fin[(size_t)(start + p + 2) * D + d]);
        s3 += bf2f(fin[(size_t)(start + p + 3) * D + d]);
    }
    for (; p < L; p++) s0 += bf2f(fin[(size_t)(start + p) * D + d]);
    out[(size_t)g * D + d] = (s0 + s1 + s2 + s3) / (float)L;
}

// ---------------------------------------------------------------------------
extern "C" void kernel_launch(void* const* d_in, const int* in_sizes, int n_in,
                              void* d_out, int out_size, void* d_ws, size_t ws_size,
                              hipStream_t stream) {
    const float* POI        = (const float*)d_in[0];
    const float* delta      = (const float*)d_in[1];
    const float* att_W      = (const float*)d_in[2];
    const float* a_src      = (const float*)d_in[3];
    const float* a_dst      = (const float*)d_in[4];
    const float* in_proj_w  = (const float*)d_in[5];
    const float* in_proj_b  = (const float*)d_in[6];
    const float* out_proj_w = (const float*)d_in[7];
    const float* out_proj_b = (const float*)d_in[8];
    const float* ln1_g      = (const float*)d_in[9];
    const float* ln1_b      = (const float*)d_in[10];
    const float* ln2_g      = (const float*)d_in[11];
    const float* ln2_b      = (const float*)d_in[12];
    const float* ffn_w1     = (const float*)d_in[13];
    const float* ffn_b1     = (const float*)d_in[14];
    const float* ffn_w2     = (const float*)d_in[15];
    const float* ffn_b2     = (const float*)d_in[16];
    const int* sess_idx     = (const int*)d_in[17];
    const int* edge_dist    = (const int*)d_in[18];
    const int* batch_ids    = (const int*)d_in[20];
    const int* node_pos     = (const int*)d_in[21];
    const int* lengths      = (const int*)d_in[22];

    int N = in_sizes[17];
    int B = in_sizes[22];
    int gb = (N + 127) / 128;
    int Npad = gb * 128;

    // ---- workspace layout in BYTES, 256-aligned blocks ---------------------
    char* base = (char*)d_ws;
    size_t off = 0;
    auto alloc = [&](size_t bytes) { size_t c = off; off = (off + bytes + 255) & ~(size_t)255; return c; };
    size_t o_csrc  = alloc(D * 4);
    size_t o_cdst  = alloc(D * 4);
    size_t o_t     = alloc(512 * 4);
    size_t o_start = alloc((size_t)B * 4);
    size_t o_mu    = alloc((size_t)N * 4);
    size_t o_ri    = alloc((size_t)N * 4);
    size_t o_u     = alloc(D * 4);
    size_t o_z     = alloc(D * 4);
    size_t o_wb    = alloc(6 * D * D * 2);
    size_t nb      = (size_t)Npad * D * 2;       // one bf16 [Npad,128] buffer
    size_t o_A = alloc(nb);
    size_t o_B = alloc(nb);
    size_t o_C = alloc(nb);
    size_t o_D = alloc(nb);
    if (ws_size < off) return;   // diagnostic: silent fail, no GPU fault

    float* c_src = (float*)(base + o_csrc);
    float* c_dst = (float*)(base + o_cdst);
    float* tb    = (float*)(base + o_t);
    int*   starts = (int*)(base + o_start);
    float* muv   = (float*)(base + o_mu);
    float* rinvv = (float*)(base + o_ri);
    float* u     = (float*)(base + o_u);
    float* z     = (float*)(base + o_z);
    unsigned short* wb = (unsigned short*)(base + o_wb);
    unsigned short* bufA = (unsigned short*)(base + o_A);
    unsigned short* bufB = (unsigned short*)(base + o_B);
    unsigned short* bufC = (unsigned short*)(base + o_C);
    unsigned short* bufD = (unsigned short*)(base + o_D);

    // ---- pipeline ----------------------------------------------------------
    prep1<<<1, 128, 0, stream>>>(att_W, a_src, a_dst, in_proj_w, in_proj_b,
                                 ln1_g, ln1_b, c_src, c_dst, u, z);
    prep2<<<512, 256, 0, stream>>>(delta, c_src, in_proj_w, out_proj_w,
                                   ffn_w1, ffn_w2, ln1_g, tb, wb);
    gather_hu<<<(N + 7) / 8, 256, 0, stream>>>(POI, sess_idx, node_pos, batch_ids,
                                               edge_dist, lengths, c_src, c_dst, tb,
                                               bufB, muv, rinvv, starts, N);    // Hu=B

    qkv_split<<<dim3(gb, 3), 256, 0, stream>>>(bufB, wb, in_proj_b, u, z, muv, rinvv,
                                               bufC, bufD, bufA, N, Npad);   // q=C, k=D, vT=A

    attn8<<<dim3(B, NHEAD), 128, 0, stream>>>(bufC, bufD, bufA, starts, lengths, bufC, Npad); // ctx=C

    outproj_ln2<<<gb, 256, 0, stream>>>(bufC, wb + 3 * D * D, out_proj_b, bufB, muv, rinvv,
                                        ln1_g, ln1_b, ln2_g, ln2_b, bufD, N);          // out2=D
    ffn_fused<<<gb, 256, 0, stream>>>(bufD, wb + 4 * D * D, ffn_b1, wb + 5 * D * D, ffn_b2,
                                      bufA, N);                                        // fin=A (vT dead)
    pool_k<<<B, 128, 0, stream>>>(bufA, starts, lengths, (float*)d_out);
}

// Round 21
// 324.798 us; speedup vs baseline: 1.0258x; 1.0258x over previous
//
#include <hip/hip_runtime.h>
#include <float.h>

// ---------------------------------------------------------------------------
// SeqGraphRepNetwork. Round 21 = round 20 with the exp2 folding FIXED:
// round-20 used libm exp2f() which expands to a precise multi-instruction
// sequence (55->62us regression). Now __builtin_amdgcn_exp2f emits exactly
// one v_exp_f32 (inputs bounded, fast path safe); log2e stays folded into
// qkv's q pre-scale. Strictly one v_mul less than round-19's __expf path.
// ---------------------------------------------------------------------------

#define D 128
#define NHEAD 4
#define HD 32
#define MAXL 160
#define MAXNK 10     // max 16-key tiles (L<=160)
#define VP 168       // Vt / Pb key pitch in ushorts
#define WP 136       // LDS tile pitch in ushorts (272B)

typedef __attribute__((ext_vector_type(8))) short short8;
typedef __attribute__((ext_vector_type(4))) float floatx4;

// ---- bf16 <-> f32 helpers (raw ushort storage, RNE) ------------------------
__device__ __forceinline__ float lo2f(unsigned u) {
    union { unsigned i; float f; } x; x.i = u << 16; return x.f;
}
__device__ __forceinline__ float hi2f(unsigned u) {
    union { unsigned i; float f; } x; x.i = u & 0xffff0000u; return x.f;
}
__device__ __forceinline__ unsigned short f2bf(float f) {
    union { float f; unsigned i; } x; x.f = f;
    unsigned r = x.i + 0x7fffu + ((x.i >> 16) & 1u);
    return (unsigned short)(r >> 16);
}
__device__ __forceinline__ unsigned pack2(float a, float b) {
    return (unsigned)f2bf(a) | ((unsigned)f2bf(b) << 16);
}
__device__ __forceinline__ float bf2f(unsigned short u) {
    union { unsigned i; float f; } x; x.i = (unsigned)u << 16; return x.f;
}

// ---- prep1: c_src/c_dst = a@att_W; u,z refold vectors (1 block, 128 thr) ---
__global__ void prep1(const float* __restrict__ att_W, const float* __restrict__ a_src,
                      const float* __restrict__ a_dst, const float* __restrict__ in_proj_w,
                      const float* __restrict__ in_proj_b, const float* __restrict__ g1,
                      const float* __restrict__ b1, float* __restrict__ c_src,
                      float* __restrict__ c_dst, float* __restrict__ u, float* __restrict__ z) {
    int p = threadIdx.x;  // 128
    float s = 0.f, d = 0.f, su = 0.f, sz = 0.f;
    for (int q = 0; q < D; q++) {
        float w = att_W[q * D + p];
        s += a_src[q] * w;
        d += a_dst[q] * w;
        float wq = in_proj_w[p * D + q];
        su += g1[q] * wq;
        sz += b1[q] * wq;
    }
    c_src[p] = s;
    c_dst[p] = d;
    u[p] = su;
    z[p] = sz + in_proj_b[p];
}

// ---- prep2: blocks 0..127 -> tb (4 buckets each); 128..511 -> bf16 weights -
// wb slots: 0 = W'q (Wq*g1), 1 = Wk, 2 = Wv, 3 = Wo, 4 = W1, 5 = W2.
__global__ void prep2(const float* __restrict__ delta, const float* __restrict__ c_src,
                      const float* __restrict__ in_proj_w, const float* __restrict__ out_proj_w,
                      const float* __restrict__ ffn_w1, const float* __restrict__ ffn_w2,
                      const float* __restrict__ ln1_g, float* __restrict__ tb,
                      unsigned short* __restrict__ wb) {
    int blk = blockIdx.x, t = threadIdx.x;
    if (blk < 128) {
        int b = blk * 4 + (t >> 6);
        int l = t & 63;
        const float* row = delta + (size_t)b * D;
        float s = row[l] * c_src[l] + row[l + 64] * c_src[l + 64];
        #pragma unroll
        for (int o = 32; o; o >>= 1) s += __shfl_down(s, o, 64);
        if (l == 0) tb[b] = s;
    } else {
        int idx = (blk - 128) * 256 + t;   // 384*256 = 98304 = 6*128*128
        int m = idx >> 14;
        int within = idx & (D * D - 1);
        float v;
        if (m == 0) v = in_proj_w[within] * ln1_g[within & (D - 1)];
        else if (m == 1) v = in_proj_w[D * D + within];
        else if (m == 2) v = in_proj_w[2 * D * D + within];
        else if (m == 3) v = out_proj_w[within];
        else if (m == 4) v = ffn_w1[within];
        else v = ffn_w2[within];
        wb[idx] = f2bf(v);
    }
}

// ---- gather_hu: block = 8 nodes + 2-row halo; HALF-WAVE per row. -----------
__launch_bounds__(256)
__global__ void gather_hu(const float* __restrict__ POI, const int* __restrict__ sess_idx,
                          const int* __restrict__ node_pos, const int* __restrict__ batch_ids,
                          const int* __restrict__ edge_dist, const int* __restrict__ lengths,
                          const float* __restrict__ c_src, const float* __restrict__ c_dst,
                          const float* __restrict__ tb, unsigned short* __restrict__ Hu,
                          float* __restrict__ muv, float* __restrict__ rinvv,
                          int* __restrict__ starts, int N) {
    __shared__ unsigned xs[10 * 64];      // 2.5 KB packed bf16x2
    __shared__ float s1s[10], s2s[10];
    int R0 = blockIdx.x * 8;
    int t = threadIdx.x;
    int hw = t >> 5, l32 = t & 31;        // 8 half-waves, 32 lanes each
    float4 cs4 = *(const float4*)(c_src + l32 * 4);
    float4 cd4 = *(const float4*)(c_dst + l32 * 4);
    #pragma unroll
    for (int i = hw; i < 10; i += 8) {
        int n = R0 - 1 + i;
        if (n >= 0 && n < N) {
            int row = sess_idx[n];
            float4 v = *(const float4*)(POI + (size_t)row * D + l32 * 4);
            ((uint2*)(xs + i * 64))[l32] = make_uint2(pack2(v.x, v.y), pack2(v.z, v.w));
            if (i >= 1 && i <= 8) {        // halo dots are never used
                float ps = v.x * cs4.x + v.y * cs4.y + v.z * cs4.z + v.w * cs4.w;
                float pd = v.x * cd4.x + v.y * cd4.y + v.z * cd4.z + v.w * cd4.w;
                #pragma unroll
                for (int o = 16; o; o >>= 1) {   // stays within the 32-half
                    ps += __shfl_down(ps, o, 64);
                    pd += __shfl_down(pd, o, 64);
                }
                if (l32 == 0) { s1s[i] = ps; s2s[i] = pd; }
            }
        }
    }
    __syncthreads();
    int j = hw;                            // one node per half-wave
    int n = R0 + j;
    if (n >= N) return;
    int g = batch_ids[n], pos = node_pos[n], L = lengths[g];
    bool hasF = pos > 0;
    bool hasB = pos < L - 1;
    float la = hasF ? (s1s[j + 1] + tb[edge_dist[n - 1 - g]]) : -FLT_MAX;
    float lb = hasB ? s2s[j + 1] : -FLT_MAX;
    float m = fmaxf(la, lb);
    float ea = hasF ? __expf(la - m) : 0.f;
    float eb = hasB ? __expf(lb - m) : 0.f;
    float inv = 1.f / (ea + eb + 1e-16f);
    float wa = ea * inv, wb = eb * inv;
    uint2 a = hasF ? ((const uint2*)(xs + j * 64))[l32] : make_uint2(0u, 0u);
    uint2 b = hasB ? ((const uint2*)(xs + (j + 2) * 64))[l32] : make_uint2(0u, 0u);
    float h0 = wa * lo2f(a.x) + wb * lo2f(b.x);
    float h1 = wa * hi2f(a.x) + wb * hi2f(b.x);
    float h2 = wa * lo2f(a.y) + wb * lo2f(b.y);
    float h3 = wa * hi2f(a.y) + wb * hi2f(b.y);
    ((uint2*)Hu)[(size_t)n * 32 + l32] = make_uint2(pack2(h0, h1), pack2(h2, h3));
    float s = h0 + h1 + h2 + h3;
    float ss = h0 * h0 + h1 * h1 + h2 * h2 + h3 * h3;
    #pragma unroll
    for (int o = 1; o < 32; o <<= 1) {     // xor <=16 stays within the half
        s += __shfl_xor(s, o, 64);
        ss += __shfl_xor(ss, o, 64);
    }
    if (l32 == 0) {
        float mu = s * (1.f / D);
        float var = ss * (1.f / D) - mu * mu;
        muv[n] = mu;
        rinvv[n] = rsqrtf(var + 1e-8f);
        if (pos == 0) starts[g] = n;
    }
}

// ---- qkv_split: grid (gb, 3); blockIdx.y = pass (0=k, 1=v, 2=q refold). ----
__launch_bounds__(256)
__global__ void qkv_split(const unsigned short* __restrict__ Hu, const unsigned short* __restrict__ wb,
                          const float* __restrict__ in_proj_b, const float* __restrict__ u,
                          const float* __restrict__ z, const float* __restrict__ muv,
                          const float* __restrict__ rinvv,
                          unsigned short* __restrict__ qo, unsigned short* __restrict__ ko,
                          unsigned short* __restrict__ vT, int M, int Npad) {
    __shared__ unsigned short Wl[128 * WP];
    int t = threadIdx.x;
    int wv = t >> 6, lane = t & 63;
    int quad = lane >> 4, l16 = lane & 15;
    int r0 = blockIdx.x * 128;
    int rbase = r0 + wv * 32;
    int p = blockIdx.y;
    // 1/sqrt(32) * log2(e): attn uses raw v_exp_f32 (2^x) directly
    const float ASCALE = 0.25504364148122793f;
    const unsigned short* W = wb + (p == 0 ? 1 : p == 1 ? 2 : 0) * (D * D);
    for (int i = t; i < 2048; i += 256) {
        int c = i >> 4, kc = (i & 15) * 8;
        *(uint4*)&Wl[c * WP + kc] = *(const uint4*)(W + c * 128 + kc);
    }
    short8 af[2][4];
    #pragma unroll
    for (int mt = 0; mt < 2; mt++) {
        int r = rbase + mt * 16 + l16;
        #pragma unroll
        for (int kk = 0; kk < 4; kk++) {
            if (r < M) af[mt][kk] = *(const short8*)(Hu + (size_t)r * D + kk * 32 + quad * 8);
            else af[mt][kk] = (short8){0, 0, 0, 0, 0, 0, 0, 0};
        }
    }
    __syncthreads();
    floatx4 acc[2][8];
    #pragma unroll
    for (int i = 0; i < 2; i++)
        #pragma unroll
        for (int j = 0; j < 8; j++) acc[i][j] = (floatx4){0.f, 0.f, 0.f, 0.f};
    #pragma unroll
    for (int kk = 0; kk < 4; kk++)
        #pragma unroll
        for (int nt = 0; nt < 8; nt++) {
            short8 bf = *(const short8*)&Wl[(nt * 16 + l16) * WP + kk * 32 + quad * 8];
            acc[0][nt] = __builtin_amdgcn_mfma_f32_16x16x32_bf16(af[0][kk], bf, acc[0][nt], 0, 0, 0);
            acc[1][nt] = __builtin_amdgcn_mfma_f32_16x16x32_bf16(af[1][kk], bf, acc[1][nt], 0, 0, 0);
        }
    __syncthreads();   // all waves done reading Wl weights
    if (p == 1) {          // vT tile: Wl[col][localnode]
        #pragma unroll
        for (int nt = 0; nt < 8; nt++) {
            int col = nt * 16 + l16;
            float bv = in_proj_b[2 * D + col];
            #pragma unroll
            for (int mt = 0; mt < 2; mt++)
                #pragma unroll
                for (int r = 0; r < 4; r++) {
                    int ln = wv * 32 + mt * 16 + quad * 4 + r;
                    Wl[col * WP + ln] = (r0 + ln < M) ? f2bf(acc[mt][nt][r] + bv)
                                                      : (unsigned short)0;
                }
        }
    } else if (p == 0) {   // k tile: Wl[localrow][col]
        #pragma unroll
        for (int nt = 0; nt < 8; nt++) {
            int col = nt * 16 + l16;
            float bv = in_proj_b[D + col];
            #pragma unroll
            for (int mt = 0; mt < 2; mt++)
                #pragma unroll
                for (int r = 0; r < 4; r++)
                    Wl[(wv * 32 + mt * 16 + quad * 4 + r) * WP + col] =
                        f2bf(acc[mt][nt][r] + bv);
        }
    } else {               // q refold tile, pre-scaled by 1/sqrt(32)*log2e
        float uc[8], zc[8];
        #pragma unroll
        for (int nt = 0; nt < 8; nt++) {
            uc[nt] = u[nt * 16 + l16];
            zc[nt] = z[nt * 16 + l16] * ASCALE;
        }
        #pragma unroll
        for (int mt = 0; mt < 2; mt++)
            #pragma unroll
            for (int r = 0; r < 4; r++) {
                int ln = wv * 32 + mt * 16 + quad * 4 + r;
                int grow = r0 + ln;
                float mr = grow < M ? muv[grow] : 0.f;
                float rr = (grow < M ? rinvv[grow] : 0.f) * ASCALE;
                #pragma unroll
                for (int nt = 0; nt < 8; nt++)
                    Wl[ln * WP + nt * 16 + l16] =
                        f2bf(rr * (acc[mt][nt][r] - mr * uc[nt]) + zc[nt]);
            }
    }
    __syncthreads();
    if (p == 1) {
        for (int i = t; i < 2048; i += 256) {
            int col = i >> 4, c8 = (i & 15) * 8;
            *(uint4*)(vT + (size_t)col * Npad + r0 + c8) = *(uint4*)&Wl[col * WP + c8];
        }
    } else {
        unsigned short* out = (p == 0) ? ko : qo;
        for (int i = t; i < 2048; i += 256) {
            int row = i >> 4, c8 = (i & 15) * 8;
            if (r0 + row < M)
                *(uint4*)(out + (size_t)(r0 + row) * D + c8) = *(uint4*)&Wl[row * WP + c8];
        }
    }
}

// ---- attn9: 2 waves; LPT remap; q prefetch; no max-pass; raw v_exp_f32
// (log2e folded into q); 1/l folded into O.
__launch_bounds__(128)
__global__ void attn9(const unsigned short* __restrict__ qb,
                      const unsigned short* __restrict__ kb,
                      const unsigned short* __restrict__ vT,
                      const int* __restrict__ starts, const int* __restrict__ lengths,
                      unsigned short* __restrict__ ctx, int Npad) {
    __shared__ unsigned short Vt[HD * VP];       // 10.5 KB [dim][key]
    __shared__ unsigned short Pb[2 * 16 * VP];   // 10.5 KB, per-wave halves
    int g = blockIdx.x;
    if (gridDim.x == 1024) {
        int bid = blockIdx.x;
        if (bid < 430) { int r = 96 - bid / 10; g = r + 97 * (bid % 10); }
        else { int b2 = bid - 430; int r = 53 - b2 / 11; g = r + 97 * (b2 % 11); }
    }
    int h = blockIdx.y;
    int start = starts[g], L = lengths[g];
    int t = threadIdx.x;
    int wv = t >> 6, lane = t & 63;
    int l16 = lane & 15, quad = lane >> 4;
    int nk = (L + 15) >> 4;
    int nk2 = (L + 31) >> 5;
    for (int i = t; i < 16 * VP; i += 128) ((unsigned*)Pb)[i] = 0u;
    int nch = nk2 * 4;
    for (int i = t; i < HD * nch; i += 128) {
        int r = i / nch, c = i - r * nch;
        *(uint4*)&Vt[r * VP + c * 8] =
            *(const uint4*)(vT + (size_t)(h * HD + r) * Npad + start + c * 8);
    }
    short8 kf[MAXNK];
    #pragma unroll
    for (int kt = 0; kt < MAXNK; kt++) {
        kf[kt] = (short8){0, 0, 0, 0, 0, 0, 0, 0};
        if (kt < nk) {
            int r = kt * 16 + l16;
            if (r < L) kf[kt] = *(const short8*)(kb + (size_t)(start + r) * D + h * HD + quad * 8);
        }
    }
    short8 qf[5];
    #pragma unroll
    for (int i = 0; i < 5; i++) {
        qf[i] = (short8){0, 0, 0, 0, 0, 0, 0, 0};
        int qt = wv + 2 * i;
        if (qt < nk) {
            int qrow = qt * 16 + l16;
            if (qrow < L)
                qf[i] = *(const short8*)(qb + (size_t)(start + qrow) * D + h * HD + quad * 8);
        }
    }
    __syncthreads();
    unsigned short* Pw = Pb + wv * 16 * VP;
    #pragma unroll
    for (int i = 0; i < 5; i++) {
        int qt = wv + 2 * i;
        if (qt >= nk) break;
        int q0 = qt * 16;
        floatx4 sacc[MAXNK];
        #pragma unroll
        for (int kt = 0; kt < MAXNK; kt++)
            if (kt < nk)
                sacc[kt] = __builtin_amdgcn_mfma_f32_16x16x32_bf16(
                    kf[kt], qf[i], (floatx4){0.f, 0.f, 0.f, 0.f}, 0, 0, 0);
        float lsum = 0.f;
        #pragma unroll
        for (int kt = 0; kt < MAXNK; kt++)
            if (kt < nk) {
                #pragma unroll
                for (int r = 0; r < 4; r++) {
                    int key = kt * 16 + quad * 4 + r;
                    // raw 2^x (one v_exp_f32; log2e pre-folded into q)
                    float p = (key < L) ? __builtin_amdgcn_exp2f(sacc[kt][r]) : 0.f;
                    sacc[kt][r] = p;
                    lsum += p;
                }
            }
        #pragma unroll
        for (int kt = 0; kt < MAXNK; kt++)
            if (kt < nk) {
                *(unsigned*)&Pw[l16 * VP + kt * 16 + quad * 4] =
                    pack2(sacc[kt][0], sacc[kt][1]);
                *(unsigned*)&Pw[l16 * VP + kt * 16 + quad * 4 + 2] =
                    pack2(sacc[kt][2], sacc[kt][3]);
            }
        lsum += __shfl_xor(lsum, 16);
        lsum += __shfl_xor(lsum, 32);
        float inv = 1.f / lsum;
        #pragma unroll
        for (int nc = 0; nc < 2; nc++) {
            floatx4 oacc = (floatx4){0.f, 0.f, 0.f, 0.f};
            #pragma unroll
            for (int kc = 0; kc < 5; kc++)
                if (kc < nk2) {
                    short8 pf = *(const short8*)&Pw[l16 * VP + kc * 32 + quad * 8];
                    short8 vf = *(const short8*)&Vt[(nc * 16 + l16) * VP + kc * 32 + quad * 8];
                    oacc = __builtin_amdgcn_mfma_f32_16x16x32_bf16(pf, vf, oacc, 0, 0, 0);
                }
            #pragma unroll
            for (int r = 0; r < 4; r++) {
                int qr = q0 + quad * 4 + r;
                if (qr < L)
                    ctx[(size_t)(start + qr) * D + h * HD + nc * 16 + l16] =
                        f2bf(oacc[r] * inv);
            }
        }
    }
}

// ---- outproj_ln2: out2 = LN2( ctx@Wo^T + bo + Q ), Q from Hu (LDS-staged) --
__launch_bounds__(256)
__global__ void outproj_ln2(const unsigned short* __restrict__ ctx, const unsigned short* __restrict__ W,
                            const float* __restrict__ bo, const unsigned short* __restrict__ Hu,
                            const float* __restrict__ muv, const float* __restrict__ rinvv,
                            const float* __restrict__ g1, const float* __restrict__ b1,
                            const float* __restrict__ g2, const float* __restrict__ b2,
                            unsigned short* __restrict__ out, int M) {
    __shared__ unsigned short Wl[128 * WP];
    int t = threadIdx.x;
    int wv = t >> 6, lane = t & 63;
    int quad = lane >> 4, l16 = lane & 15;
    int r0 = blockIdx.x * 128;
    int rbase = r0 + wv * 32;
    for (int i = t; i < 2048; i += 256) {
        int c = i >> 4, kc = (i & 15) * 8;
        *(uint4*)&Wl[c * WP + kc] = *(const uint4*)(W + c * 128 + kc);
    }
    __syncthreads();
    floatx4 acc[2][8];
    #pragma unroll
    for (int i = 0; i < 2; i++)
        #pragma unroll
        for (int j = 0; j < 8; j++) acc[i][j] = (floatx4){0.f, 0.f, 0.f, 0.f};
    #pragma unroll
    for (int kk = 0; kk < 4; kk++) {
        short8 af[2];
        #pragma unroll
        for (int mt = 0; mt < 2; mt++) {
            int r = rbase + mt * 16 + l16;
            if (r < M) af[mt] = *(const short8*)(ctx + (size_t)r * D + kk * 32 + quad * 8);
            else af[mt] = (short8){0, 0, 0, 0, 0, 0, 0, 0};
        }
        #pragma unroll
        for (int nt = 0; nt < 8; nt++) {
            short8 bf = *(const short8*)&Wl[(nt * 16 + l16) * WP + kk * 32 + quad * 8];
            acc[0][nt] = __builtin_amdgcn_mfma_f32_16x16x32_bf16(af[0], bf, acc[0][nt], 0, 0, 0);
            acc[1][nt] = __builtin_amdgcn_mfma_f32_16x16x32_bf16(af[1], bf, acc[1][nt], 0, 0, 0);
        }
    }
    __syncthreads();   // done reading Wo
    for (int i = t; i < 2048; i += 256) {
        int row = i >> 4, c8 = (i & 15) * 8;
        uint4 hv = make_uint4(0u, 0u, 0u, 0u);
        if (r0 + row < M) hv = *(const uint4*)(Hu + (size_t)(r0 + row) * D + c8);
        *(uint4*)&Wl[row * WP + c8] = hv;
    }
    __syncthreads();
    float g1c[8], b1c[8], boc[8], g2c[8], b2c[8];
    #pragma unroll
    for (int nt = 0; nt < 8; nt++) {
        int col = nt * 16 + l16;
        g1c[nt] = g1[col]; b1c[nt] = b1[col]; boc[nt] = bo[col];
        g2c[nt] = g2[col]; b2c[nt] = b2[col];
    }
    #pragma unroll
    for (int mt = 0; mt < 2; mt++) {
        #pragma unroll
        for (int r = 0; r < 4; r++) {
            int lrow = wv * 32 + mt * 16 + quad * 4 + r;
            int grow = r0 + lrow;
            bool ok = grow < M;
            float mr = ok ? muv[grow] : 0.f;
            float rr = ok ? rinvv[grow] : 0.f;
            float vv[8];
            float s = 0.f, ss = 0.f;
            #pragma unroll
            for (int nt = 0; nt < 8; nt++) {
                float huv = bf2f(Wl[lrow * WP + nt * 16 + l16]);
                float qv = (huv - mr) * rr * g1c[nt] + b1c[nt];
                float v = acc[mt][nt][r] + boc[nt] + qv;
                vv[nt] = v;
                s += v; ss += v * v;
            }
            #pragma unroll
            for (int o = 1; o < 16; o <<= 1) {
                s += __shfl_xor(s, o, 64);
                ss += __shfl_xor(ss, o, 64);
            }
            float mu = s * (1.f / D);
            float var = ss * (1.f / D) - mu * mu;
            float rinv = rsqrtf(var + 1e-8f);
            #pragma unroll
            for (int nt = 0; nt < 8; nt++)
                Wl[lrow * WP + nt * 16 + l16] =
                    f2bf((vv[nt] - mu) * rinv * g2c[nt] + b2c[nt]);
        }
    }
    __syncthreads();
    for (int i = t; i < 2048; i += 256) {
        int row = i >> 4, c8 = (i & 15) * 8;
        if (r0 + row < M)
            *(uint4*)(out + (size_t)(r0 + row) * D + c8) = *(uint4*)&Wl[row * WP + c8];
    }
}

// ---- ffn_fused: fin = out2 + relu(out2@W1^T+b1)@W2^T + b2 ------------------
__launch_bounds__(256)
__global__ void ffn_fused(const unsigned short* __restrict__ out2, const unsigned short* __restrict__ W1,
                          const float* __restrict__ b1f, const unsigned short* __restrict__ W2,
                          const float* __restrict__ b2f, unsigned short* __restrict__ fin, int M) {
    __shared__ unsigned short Wl[128 * WP];
    int t = threadIdx.x;
    int wv = t >> 6, lane = t & 63;
    int quad = lane >> 4, l16 = lane & 15;
    int r0 = blockIdx.x * 128;
    int rbase = r0 + wv * 32;
    int lbase = wv * 32;
    for (int i = t; i < 2048; i += 256) {    // stage W1
        int c = i >> 4, kc = (i & 15) * 8;
        *(uint4*)&Wl[c * WP + kc] = *(const uint4*)(W1 + c * 128 + kc);
    }
    short8 af[2][4];
    #pragma unroll
    for (int mt = 0; mt < 2; mt++) {
        int r = rbase + mt * 16 + l16;
        #pragma unroll
        for (int kk = 0; kk < 4; kk++) {
            if (r < M) af[mt][kk] = *(const short8*)(out2 + (size_t)r * D + kk * 32 + quad * 8);
            else af[mt][kk] = (short8){0, 0, 0, 0, 0, 0, 0, 0};
        }
    }
    __syncthreads();
    floatx4 acc[2][8];
    #pragma unroll
    for (int i = 0; i < 2; i++)
        #pragma unroll
        for (int j = 0; j < 8; j++) acc[i][j] = (floatx4){0.f, 0.f, 0.f, 0.f};
    #pragma unroll
    for (int kk = 0; kk < 4; kk++)
        #pragma unroll
        for (int nt = 0; nt < 8; nt++) {
            short8 bf = *(const short8*)&Wl[(nt * 16 + l16) * WP + kk * 32 + quad * 8];
            acc[0][nt] = __builtin_amdgcn_mfma_f32_16x16x32_bf16(af[0][kk], bf, acc[0][nt], 0, 0, 0);
            acc[1][nt] = __builtin_amdgcn_mfma_f32_16x16x32_bf16(af[1][kk], bf, acc[1][nt], 0, 0, 0);
        }
    __syncthreads();   // done reading W1
    #pragma unroll
    for (int nt = 0; nt < 8; nt++) {
        int col = nt * 16 + l16;
        float bv = b1f[col];
        #pragma unroll
        for (int mt = 0; mt < 2; mt++)
            #pragma unroll
            for (int r = 0; r < 4; r++)
                Wl[(lbase + mt * 16 + quad * 4 + r) * WP + col] =
                    f2bf(fmaxf(acc[mt][nt][r] + bv, 0.f));
    }
    __syncthreads();
    short8 af2[2][4];
    #pragma unroll
    for (int mt = 0; mt < 2; mt++)
        #pragma unroll
        for (int kk = 0; kk < 4; kk++)
            af2[mt][kk] = *(const short8*)&Wl[(lbase + mt * 16 + l16) * WP + kk * 32 + quad * 8];
    __syncthreads();
    for (int i = t; i < 2048; i += 256) {    // stage W2
        int c = i >> 4, kc = (i & 15) * 8;
        *(uint4*)&Wl[c * WP + kc] = *(const uint4*)(W2 + c * 128 + kc);
    }
    __syncthreads();
    #pragma unroll
    for (int i = 0; i < 2; i++)
        #pragma unroll
        for (int j = 0; j < 8; j++) acc[i][j] = (floatx4){0.f, 0.f, 0.f, 0.f};
    #pragma unroll
    for (int kk = 0; kk < 4; kk++)
        #pragma unroll
        for (int nt = 0; nt < 8; nt++) {
            short8 bf = *(const short8*)&Wl[(nt * 16 + l16) * WP + kk * 32 + quad * 8];
            acc[0][nt] = __builtin_amdgcn_mfma_f32_16x16x32_bf16(af2[0][kk], bf, acc[0][nt], 0, 0, 0);
            acc[1][nt] = __builtin_amdgcn_mfma_f32_16x16x32_bf16(af2[1][kk], bf, acc[1][nt], 0, 0, 0);
        }
    __syncthreads();   // done reading W2
    #pragma unroll
    for (int nt = 0; nt < 8; nt++) {
        int col = nt * 16 + l16;
        float bv = b2f[col];
        #pragma unroll
        for (int mt = 0; mt < 2; mt++)
            #pragma unroll
            for (int r = 0; r < 4; r++)
                Wl[(lbase + mt * 16 + quad * 4 + r) * WP + col] = f2bf(acc[mt][nt][r] + bv);
    }
    __syncthreads();
    for (int i = t; i < 2048; i += 256) {
        int row = i >> 4, c8 = (i & 15) * 8;
        int grow = r0 + row;
        if (grow < M) {
            uint4 a = *(uint4*)&Wl[row * WP + c8];
            uint4 b = *(const uint4*)(out2 + (size_t)grow * D + c8);
            uint4 o;
            o.x = pack2(lo2f(a.x) + lo2f(b.x), hi2f(a.x) + hi2f(b.x));
            o.y = pack2(lo2f(a.y) + lo2f(b.y), hi2f(a.y) + hi2f(b.y));
            o.z = pack2(lo2f(a.z) + lo2f(b.z), hi2f(a.z) + hi2f(b.z));
            o.w = pack2(lo2f(a.w) + lo2f(b.w), hi2f(a.w) + hi2f(b.w));
            *(uint4*)(fin + (size_t)grow * D + c8) = o;
        }
    }
}

// ---- masked mean pool (bf16 -> fp32 out) -----------------------------------
__global__ void pool_k(const unsigned short* __restrict__ fin, const int* __restrict__ starts,
                       const int* __restrict__ lengths, float* __restrict__ out) {
    int g = blockIdx.x, d = threadIdx.x;  // 128 threads
    int start = starts[g], L = lengths[g];
    float s0 = 0.f, s1 = 0.f, s2 = 0.f, s3 = 0.f;
    int p = 0;
    for (; p + 4 <= L; p += 4) {
        s0 += bf2f(fin[(size_t)(start + p) * D + d]);
        s1 += bf2f(fin[(size_t)(start + p + 1) * D + d]);
        s2 += bf2f(fin[(size_t)(start + p + 2) * D + d]);
        s3 += bf2f(fin[(size_t)(start + p + 3) * D + d]);
    }
    for (; p < L; p++) s0 += bf2f(fin[(size_t)(start + p) * D + d]);
    out[(size_t)g * D + d] = (s0 + s1 + s2 + s3) / (float)L;
}

// ---------------------------------------------------------------------------
extern "C" void kernel_launch(void* const* d_in, const int* in_sizes, int n_in,
                              void* d_out, int out_size, void* d_ws, size_t ws_size,
                              hipStream_t stream) {
    const float* POI        = (const float*)d_in[0];
    const float* delta      = (const float*)d_in[1];
    const float* att_W      = (const float*)d_in[2];
    const float* a_src      = (const float*)d_in[3];
    const float* a_dst      = (const float*)d_in[4];
    const float* in_proj_w  = (const float*)d_in[5];
    const float* in_proj_b  = (const float*)d_in[6];
    const float* out_proj_w = (const float*)d_in[7];
    const float* out_proj_b = (const float*)d_in[8];
    const float* ln1_g      = (const float*)d_in[9];
    const float* ln1_b      = (const float*)d_in[10];
    const float* ln2_g      = (const float*)d_in[11];
    const float* ln2_b      = (const float*)d_in[12];
    const float* ffn_w1     = (const float*)d_in[13];
    const float* ffn_b1     = (const float*)d_in[14];
    const float* ffn_w2     = (const float*)d_in[15];
    const float* ffn_b2     = (const float*)d_in[16];
    const int* sess_idx     = (const int*)d_in[17];
    const int* edge_dist    = (const int*)d_in[18];
    const int* batch_ids    = (const int*)d_in[20];
    const int* node_pos     = (const int*)d_in[21];
    const int* lengths      = (const int*)d_in[22];

    int N = in_sizes[17];
    int B = in_sizes[22];
    int gb = (N + 127) / 128;
    int Npad = gb * 128;

    // ---- workspace layout in BYTES, 256-aligned blocks ---------------------
    char* base = (char*)d_ws;
    size_t off = 0;
    auto alloc = [&](size_t bytes) { size_t c = off; off = (off + bytes + 255) & ~(size_t)255; return c; };
    size_t o_csrc  = alloc(D * 4);
    size_t o_cdst  = alloc(D * 4);
    size_t o_t     = alloc(512 * 4);
    size_t o_start = alloc((size_t)B * 4);
    size_t o_mu    = alloc((size_t)N * 4);
    size_t o_ri    = alloc((size_t)N * 4);
    size_t o_u     = alloc(D * 4);
    size_t o_z     = alloc(D * 4);
    size_t o_wb    = alloc(6 * D * D * 2);
    size_t nb      = (size_t)Npad * D * 2;       // one bf16 [Npad,128] buffer
    size_t o_A = alloc(nb);
    size_t o_B = alloc(nb);
    size_t o_C = alloc(nb);
    size_t o_D = alloc(nb);
    if (ws_size < off) return;   // diagnostic: silent fail, no GPU fault

    float* c_src = (float*)(base + o_csrc);
    float* c_dst = (float*)(base + o_cdst);
    float* tb    = (float*)(base + o_t);
    int*   starts = (int*)(base + o_start);
    float* muv   = (float*)(base + o_mu);
    float* rinvv = (float*)(base + o_ri);
    float* u     = (float*)(base + o_u);
    float* z     = (float*)(base + o_z);
    unsigned short* wb = (unsigned short*)(base + o_wb);
    unsigned short* bufA = (unsigned short*)(base + o_A);
    unsigned short* bufB = (unsigned short*)(base + o_B);
    unsigned short* bufC = (unsigned short*)(base + o_C);
    unsigned short* bufD = (unsigned short*)(base + o_D);

    // ---- pipeline ----------------------------------------------------------
    prep1<<<1, 128, 0, stream>>>(att_W, a_src, a_dst, in_proj_w, in_proj_b,
                                 ln1_g, ln1_b, c_src, c_dst, u, z);
    prep2<<<512, 256, 0, stream>>>(delta, c_src, in_proj_w, out_proj_w,
                                   ffn_w1, ffn_w2, ln1_g, tb, wb);
    gather_hu<<<(N + 7) / 8, 256, 0, stream>>>(POI, sess_idx, node_pos, batch_ids,
                                               edge_dist, lengths, c_src, c_dst, tb,
                                               bufB, muv, rinvv, starts, N);    // Hu=B

    qkv_split<<<dim3(gb, 3), 256, 0, stream>>>(bufB, wb, in_proj_b, u, z, muv, rinvv,
                                               bufC, bufD, bufA, N, Npad);   // q=C, k=D, vT=A

    attn9<<<dim3(B, NHEAD), 128, 0, stream>>>(bufC, bufD, bufA, starts, lengths, bufC, Npad); // ctx=C

    outproj_ln2<<<gb, 256, 0, stream>>>(bufC, wb + 3 * D * D, out_proj_b, bufB, muv, rinvv,
                                        ln1_g, ln1_b, ln2_g, ln2_b, bufD, N);          // out2=D
    ffn_fused<<<gb, 256, 0, stream>>>(bufD, wb + 4 * D * D, ffn_b1, wb + 5 * D * D, ffn_b2,
                                      bufA, N);                                        // fin=A (vT dead)
    pool_k<<<B, 128, 0, stream>>>(bufA, starts, lengths, (float*)d_out);
}

// Round 22
// 318.292 us; speedup vs baseline: 1.0468x; 1.0204x over previous
//
#include <hip/hip_runtime.h>
#include <float.h>

// ---------------------------------------------------------------------------
// SeqGraphRepNetwork. Round 22 = round 21 (best: 324.8us) + pool_k
// restructured: 512 threads / 4 row-quarters per session (serial load chain
// cut 4x, 8 waves/block), partials combined via 2KB LDS. Everything else
// identical (attn9 exp2 builtin, qkv_split grid.y=3, halo gather, LPT).
// ---------------------------------------------------------------------------

#define D 128
#define NHEAD 4
#define HD 32
#define MAXL 160
#define MAXNK 10     // max 16-key tiles (L<=160)
#define VP 168       // Vt / Pb key pitch in ushorts
#define WP 136       // LDS tile pitch in ushorts (272B)

typedef __attribute__((ext_vector_type(8))) short short8;
typedef __attribute__((ext_vector_type(4))) float floatx4;

// ---- bf16 <-> f32 helpers (raw ushort storage, RNE) ------------------------
__device__ __forceinline__ float lo2f(unsigned u) {
    union { unsigned i; float f; } x; x.i = u << 16; return x.f;
}
__device__ __forceinline__ float hi2f(unsigned u) {
    union { unsigned i; float f; } x; x.i = u & 0xffff0000u; return x.f;
}
__device__ __forceinline__ unsigned short f2bf(float f) {
    union { float f; unsigned i; } x; x.f = f;
    unsigned r = x.i + 0x7fffu + ((x.i >> 16) & 1u);
    return (unsigned short)(r >> 16);
}
__device__ __forceinline__ unsigned pack2(float a, float b) {
    return (unsigned)f2bf(a) | ((unsigned)f2bf(b) << 16);
}
__device__ __forceinline__ float bf2f(unsigned short u) {
    union { unsigned i; float f; } x; x.i = (unsigned)u << 16; return x.f;
}

// ---- prep1: c_src/c_dst = a@att_W; u,z refold vectors (1 block, 128 thr) ---
__global__ void prep1(const float* __restrict__ att_W, const float* __restrict__ a_src,
                      const float* __restrict__ a_dst, const float* __restrict__ in_proj_w,
                      const float* __restrict__ in_proj_b, const float* __restrict__ g1,
                      const float* __restrict__ b1, float* __restrict__ c_src,
                      float* __restrict__ c_dst, float* __restrict__ u, float* __restrict__ z) {
    int p = threadIdx.x;  // 128
    float s = 0.f, d = 0.f, su = 0.f, sz = 0.f;
    for (int q = 0; q < D; q++) {
        float w = att_W[q * D + p];
        s += a_src[q] * w;
        d += a_dst[q] * w;
        float wq = in_proj_w[p * D + q];
        su += g1[q] * wq;
        sz += b1[q] * wq;
    }
    c_src[p] = s;
    c_dst[p] = d;
    u[p] = su;
    z[p] = sz + in_proj_b[p];
}

// ---- prep2: blocks 0..127 -> tb (4 buckets each); 128..511 -> bf16 weights -
// wb slots: 0 = W'q (Wq*g1), 1 = Wk, 2 = Wv, 3 = Wo, 4 = W1, 5 = W2.
__global__ void prep2(const float* __restrict__ delta, const float* __restrict__ c_src,
                      const float* __restrict__ in_proj_w, const float* __restrict__ out_proj_w,
                      const float* __restrict__ ffn_w1, const float* __restrict__ ffn_w2,
                      const float* __restrict__ ln1_g, float* __restrict__ tb,
                      unsigned short* __restrict__ wb) {
    int blk = blockIdx.x, t = threadIdx.x;
    if (blk < 128) {
        int b = blk * 4 + (t >> 6);
        int l = t & 63;
        const float* row = delta + (size_t)b * D;
        float s = row[l] * c_src[l] + row[l + 64] * c_src[l + 64];
        #pragma unroll
        for (int o = 32; o; o >>= 1) s += __shfl_down(s, o, 64);
        if (l == 0) tb[b] = s;
    } else {
        int idx = (blk - 128) * 256 + t;   // 384*256 = 98304 = 6*128*128
        int m = idx >> 14;
        int within = idx & (D * D - 1);
        float v;
        if (m == 0) v = in_proj_w[within] * ln1_g[within & (D - 1)];
        else if (m == 1) v = in_proj_w[D * D + within];
        else if (m == 2) v = in_proj_w[2 * D * D + within];
        else if (m == 3) v = out_proj_w[within];
        else if (m == 4) v = ffn_w1[within];
        else v = ffn_w2[within];
        wb[idx] = f2bf(v);
    }
}

// ---- gather_hu: block = 8 nodes + 2-row halo; HALF-WAVE per row. -----------
__launch_bounds__(256)
__global__ void gather_hu(const float* __restrict__ POI, const int* __restrict__ sess_idx,
                          const int* __restrict__ node_pos, const int* __restrict__ batch_ids,
                          const int* __restrict__ edge_dist, const int* __restrict__ lengths,
                          const float* __restrict__ c_src, const float* __restrict__ c_dst,
                          const float* __restrict__ tb, unsigned short* __restrict__ Hu,
                          float* __restrict__ muv, float* __restrict__ rinvv,
                          int* __restrict__ starts, int N) {
    __shared__ unsigned xs[10 * 64];      // 2.5 KB packed bf16x2
    __shared__ float s1s[10], s2s[10];
    int R0 = blockIdx.x * 8;
    int t = threadIdx.x;
    int hw = t >> 5, l32 = t & 31;        // 8 half-waves, 32 lanes each
    float4 cs4 = *(const float4*)(c_src + l32 * 4);
    float4 cd4 = *(const float4*)(c_dst + l32 * 4);
    #pragma unroll
    for (int i = hw; i < 10; i += 8) {
        int n = R0 - 1 + i;
        if (n >= 0 && n < N) {
            int row = sess_idx[n];
            float4 v = *(const float4*)(POI + (size_t)row * D + l32 * 4);
            ((uint2*)(xs + i * 64))[l32] = make_uint2(pack2(v.x, v.y), pack2(v.z, v.w));
            if (i >= 1 && i <= 8) {        // halo dots are never used
                float ps = v.x * cs4.x + v.y * cs4.y + v.z * cs4.z + v.w * cs4.w;
                float pd = v.x * cd4.x + v.y * cd4.y + v.z * cd4.z + v.w * cd4.w;
                #pragma unroll
                for (int o = 16; o; o >>= 1) {   // stays within the 32-half
                    ps += __shfl_down(ps, o, 64);
                    pd += __shfl_down(pd, o, 64);
                }
                if (l32 == 0) { s1s[i] = ps; s2s[i] = pd; }
            }
        }
    }
    __syncthreads();
    int j = hw;                            // one node per half-wave
    int n = R0 + j;
    if (n >= N) return;
    int g = batch_ids[n], pos = node_pos[n], L = lengths[g];
    bool hasF = pos > 0;
    bool hasB = pos < L - 1;
    float la = hasF ? (s1s[j + 1] + tb[edge_dist[n - 1 - g]]) : -FLT_MAX;
    float lb = hasB ? s2s[j + 1] : -FLT_MAX;
    float m = fmaxf(la, lb);
    float ea = hasF ? __expf(la - m) : 0.f;
    float eb = hasB ? __expf(lb - m) : 0.f;
    float inv = 1.f / (ea + eb + 1e-16f);
    float wa = ea * inv, wb = eb * inv;
    uint2 a = hasF ? ((const uint2*)(xs + j * 64))[l32] : make_uint2(0u, 0u);
    uint2 b = hasB ? ((const uint2*)(xs + (j + 2) * 64))[l32] : make_uint2(0u, 0u);
    float h0 = wa * lo2f(a.x) + wb * lo2f(b.x);
    float h1 = wa * hi2f(a.x) + wb * hi2f(b.x);
    float h2 = wa * lo2f(a.y) + wb * lo2f(b.y);
    float h3 = wa * hi2f(a.y) + wb * hi2f(b.y);
    ((uint2*)Hu)[(size_t)n * 32 + l32] = make_uint2(pack2(h0, h1), pack2(h2, h3));
    float s = h0 + h1 + h2 + h3;
    float ss = h0 * h0 + h1 * h1 + h2 * h2 + h3 * h3;
    #pragma unroll
    for (int o = 1; o < 32; o <<= 1) {     // xor <=16 stays within the half
        s += __shfl_xor(s, o, 64);
        ss += __shfl_xor(ss, o, 64);
    }
    if (l32 == 0) {
        float mu = s * (1.f / D);
        float var = ss * (1.f / D) - mu * mu;
        muv[n] = mu;
        rinvv[n] = rsqrtf(var + 1e-8f);
        if (pos == 0) starts[g] = n;
    }
}

// ---- qkv_split: grid (gb, 3); blockIdx.y = pass (0=k, 1=v, 2=q refold). ----
__launch_bounds__(256)
__global__ void qkv_split(const unsigned short* __restrict__ Hu, const unsigned short* __restrict__ wb,
                          const float* __restrict__ in_proj_b, const float* __restrict__ u,
                          const float* __restrict__ z, const float* __restrict__ muv,
                          const float* __restrict__ rinvv,
                          unsigned short* __restrict__ qo, unsigned short* __restrict__ ko,
                          unsigned short* __restrict__ vT, int M, int Npad) {
    __shared__ unsigned short Wl[128 * WP];
    int t = threadIdx.x;
    int wv = t >> 6, lane = t & 63;
    int quad = lane >> 4, l16 = lane & 15;
    int r0 = blockIdx.x * 128;
    int rbase = r0 + wv * 32;
    int p = blockIdx.y;
    // 1/sqrt(32) * log2(e): attn uses raw v_exp_f32 (2^x) directly
    const float ASCALE = 0.25504364148122793f;
    const unsigned short* W = wb + (p == 0 ? 1 : p == 1 ? 2 : 0) * (D * D);
    for (int i = t; i < 2048; i += 256) {
        int c = i >> 4, kc = (i & 15) * 8;
        *(uint4*)&Wl[c * WP + kc] = *(const uint4*)(W + c * 128 + kc);
    }
    short8 af[2][4];
    #pragma unroll
    for (int mt = 0; mt < 2; mt++) {
        int r = rbase + mt * 16 + l16;
        #pragma unroll
        for (int kk = 0; kk < 4; kk++) {
            if (r < M) af[mt][kk] = *(const short8*)(Hu + (size_t)r * D + kk * 32 + quad * 8);
            else af[mt][kk] = (short8){0, 0, 0, 0, 0, 0, 0, 0};
        }
    }
    __syncthreads();
    floatx4 acc[2][8];
    #pragma unroll
    for (int i = 0; i < 2; i++)
        #pragma unroll
        for (int j = 0; j < 8; j++) acc[i][j] = (floatx4){0.f, 0.f, 0.f, 0.f};
    #pragma unroll
    for (int kk = 0; kk < 4; kk++)
        #pragma unroll
        for (int nt = 0; nt < 8; nt++) {
            short8 bf = *(const short8*)&Wl[(nt * 16 + l16) * WP + kk * 32 + quad * 8];
            acc[0][nt] = __builtin_amdgcn_mfma_f32_16x16x32_bf16(af[0][kk], bf, acc[0][nt], 0, 0, 0);
            acc[1][nt] = __builtin_amdgcn_mfma_f32_16x16x32_bf16(af[1][kk], bf, acc[1][nt], 0, 0, 0);
        }
    __syncthreads();   // all waves done reading Wl weights
    if (p == 1) {          // vT tile: Wl[col][localnode]
        #pragma unroll
        for (int nt = 0; nt < 8; nt++) {
            int col = nt * 16 + l16;
            float bv = in_proj_b[2 * D + col];
            #pragma unroll
            for (int mt = 0; mt < 2; mt++)
                #pragma unroll
                for (int r = 0; r < 4; r++) {
                    int ln = wv * 32 + mt * 16 + quad * 4 + r;
                    Wl[col * WP + ln] = (r0 + ln < M) ? f2bf(acc[mt][nt][r] + bv)
                                                      : (unsigned short)0;
                }
        }
    } else if (p == 0) {   // k tile: Wl[localrow][col]
        #pragma unroll
        for (int nt = 0; nt < 8; nt++) {
            int col = nt * 16 + l16;
            float bv = in_proj_b[D + col];
            #pragma unroll
            for (int mt = 0; mt < 2; mt++)
                #pragma unroll
                for (int r = 0; r < 4; r++)
                    Wl[(wv * 32 + mt * 16 + quad * 4 + r) * WP + col] =
                        f2bf(acc[mt][nt][r] + bv);
        }
    } else {               // q refold tile, pre-scaled by 1/sqrt(32)*log2e
        float uc[8], zc[8];
        #pragma unroll
        for (int nt = 0; nt < 8; nt++) {
            uc[nt] = u[nt * 16 + l16];
            zc[nt] = z[nt * 16 + l16] * ASCALE;
        }
        #pragma unroll
        for (int mt = 0; mt < 2; mt++)
            #pragma unroll
            for (int r = 0; r < 4; r++) {
                int ln = wv * 32 + mt * 16 + quad * 4 + r;
                int grow = r0 + ln;
                float mr = grow < M ? muv[grow] : 0.f;
                float rr = (grow < M ? rinvv[grow] : 0.f) * ASCALE;
                #pragma unroll
                for (int nt = 0; nt < 8; nt++)
                    Wl[ln * WP + nt * 16 + l16] =
                        f2bf(rr * (acc[mt][nt][r] - mr * uc[nt]) + zc[nt]);
            }
    }
    __syncthreads();
    if (p == 1) {
        for (int i = t; i < 2048; i += 256) {
            int col = i >> 4, c8 = (i & 15) * 8;
            *(uint4*)(vT + (size_t)col * Npad + r0 + c8) = *(uint4*)&Wl[col * WP + c8];
        }
    } else {
        unsigned short* out = (p == 0) ? ko : qo;
        for (int i = t; i < 2048; i += 256) {
            int row = i >> 4, c8 = (i & 15) * 8;
            if (r0 + row < M)
                *(uint4*)(out + (size_t)(r0 + row) * D + c8) = *(uint4*)&Wl[row * WP + c8];
        }
    }
}

// ---- attn9: 2 waves; LPT remap; q prefetch; no max-pass; raw v_exp_f32
// (log2e folded into q); 1/l folded into O.
__launch_bounds__(128)
__global__ void attn9(const unsigned short* __restrict__ qb,
                      const unsigned short* __restrict__ kb,
                      const unsigned short* __restrict__ vT,
                      const int* __restrict__ starts, const int* __restrict__ lengths,
                      unsigned short* __restrict__ ctx, int Npad) {
    __shared__ unsigned short Vt[HD * VP];       // 10.5 KB [dim][key]
    __shared__ unsigned short Pb[2 * 16 * VP];   // 10.5 KB, per-wave halves
    int g = blockIdx.x;
    if (gridDim.x == 1024) {
        int bid = blockIdx.x;
        if (bid < 430) { int r = 96 - bid / 10; g = r + 97 * (bid % 10); }
        else { int b2 = bid - 430; int r = 53 - b2 / 11; g = r + 97 * (b2 % 11); }
    }
    int h = blockIdx.y;
    int start = starts[g], L = lengths[g];
    int t = threadIdx.x;
    int wv = t >> 6, lane = t & 63;
    int l16 = lane & 15, quad = lane >> 4;
    int nk = (L + 15) >> 4;
    int nk2 = (L + 31) >> 5;
    for (int i = t; i < 16 * VP; i += 128) ((unsigned*)Pb)[i] = 0u;
    int nch = nk2 * 4;
    for (int i = t; i < HD * nch; i += 128) {
        int r = i / nch, c = i - r * nch;
        *(uint4*)&Vt[r * VP + c * 8] =
            *(const uint4*)(vT + (size_t)(h * HD + r) * Npad + start + c * 8);
    }
    short8 kf[MAXNK];
    #pragma unroll
    for (int kt = 0; kt < MAXNK; kt++) {
        kf[kt] = (short8){0, 0, 0, 0, 0, 0, 0, 0};
        if (kt < nk) {
            int r = kt * 16 + l16;
            if (r < L) kf[kt] = *(const short8*)(kb + (size_t)(start + r) * D + h * HD + quad * 8);
        }
    }
    short8 qf[5];
    #pragma unroll
    for (int i = 0; i < 5; i++) {
        qf[i] = (short8){0, 0, 0, 0, 0, 0, 0, 0};
        int qt = wv + 2 * i;
        if (qt < nk) {
            int qrow = qt * 16 + l16;
            if (qrow < L)
                qf[i] = *(const short8*)(qb + (size_t)(start + qrow) * D + h * HD + quad * 8);
        }
    }
    __syncthreads();
    unsigned short* Pw = Pb + wv * 16 * VP;
    #pragma unroll
    for (int i = 0; i < 5; i++) {
        int qt = wv + 2 * i;
        if (qt >= nk) break;
        int q0 = qt * 16;
        floatx4 sacc[MAXNK];
        #pragma unroll
        for (int kt = 0; kt < MAXNK; kt++)
            if (kt < nk)
                sacc[kt] = __builtin_amdgcn_mfma_f32_16x16x32_bf16(
                    kf[kt], qf[i], (floatx4){0.f, 0.f, 0.f, 0.f}, 0, 0, 0);
        float lsum = 0.f;
        #pragma unroll
        for (int kt = 0; kt < MAXNK; kt++)
            if (kt < nk) {
                #pragma unroll
                for (int r = 0; r < 4; r++) {
                    int key = kt * 16 + quad * 4 + r;
                    // raw 2^x (one v_exp_f32; log2e pre-folded into q)
                    float p = (key < L) ? __builtin_amdgcn_exp2f(sacc[kt][r]) : 0.f;
                    sacc[kt][r] = p;
                    lsum += p;
                }
            }
        #pragma unroll
        for (int kt = 0; kt < MAXNK; kt++)
            if (kt < nk) {
                *(unsigned*)&Pw[l16 * VP + kt * 16 + quad * 4] =
                    pack2(sacc[kt][0], sacc[kt][1]);
                *(unsigned*)&Pw[l16 * VP + kt * 16 + quad * 4 + 2] =
                    pack2(sacc[kt][2], sacc[kt][3]);
            }
        lsum += __shfl_xor(lsum, 16);
        lsum += __shfl_xor(lsum, 32);
        float inv = 1.f / lsum;
        #pragma unroll
        for (int nc = 0; nc < 2; nc++) {
            floatx4 oacc = (floatx4){0.f, 0.f, 0.f, 0.f};
            #pragma unroll
            for (int kc = 0; kc < 5; kc++)
                if (kc < nk2) {
                    short8 pf = *(const short8*)&Pw[l16 * VP + kc * 32 + quad * 8];
                    short8 vf = *(const short8*)&Vt[(nc * 16 + l16) * VP + kc * 32 + quad * 8];
                    oacc = __builtin_amdgcn_mfma_f32_16x16x32_bf16(pf, vf, oacc, 0, 0, 0);
                }
            #pragma unroll
            for (int r = 0; r < 4; r++) {
                int qr = q0 + quad * 4 + r;
                if (qr < L)
                    ctx[(size_t)(start + qr) * D + h * HD + nc * 16 + l16] =
                        f2bf(oacc[r] * inv);
            }
        }
    }
}

// ---- outproj_ln2: out2 = LN2( ctx@Wo^T + bo + Q ), Q from Hu (LDS-staged) --
__launch_bounds__(256)
__global__ void outproj_ln2(const unsigned short* __restrict__ ctx, const unsigned short* __restrict__ W,
                            const float* __restrict__ bo, const unsigned short* __restrict__ Hu,
                            const float* __restrict__ muv, const float* __restrict__ rinvv,
                            const float* __restrict__ g1, const float* __restrict__ b1,
                            const float* __restrict__ g2, const float* __restrict__ b2,
                            unsigned short* __restrict__ out, int M) {
    __shared__ unsigned short Wl[128 * WP];
    int t = threadIdx.x;
    int wv = t >> 6, lane = t & 63;
    int quad = lane >> 4, l16 = lane & 15;
    int r0 = blockIdx.x * 128;
    int rbase = r0 + wv * 32;
    for (int i = t; i < 2048; i += 256) {
        int c = i >> 4, kc = (i & 15) * 8;
        *(uint4*)&Wl[c * WP + kc] = *(const uint4*)(W + c * 128 + kc);
    }
    __syncthreads();
    floatx4 acc[2][8];
    #pragma unroll
    for (int i = 0; i < 2; i++)
        #pragma unroll
        for (int j = 0; j < 8; j++) acc[i][j] = (floatx4){0.f, 0.f, 0.f, 0.f};
    #pragma unroll
    for (int kk = 0; kk < 4; kk++) {
        short8 af[2];
        #pragma unroll
        for (int mt = 0; mt < 2; mt++) {
            int r = rbase + mt * 16 + l16;
            if (r < M) af[mt] = *(const short8*)(ctx + (size_t)r * D + kk * 32 + quad * 8);
            else af[mt] = (short8){0, 0, 0, 0, 0, 0, 0, 0};
        }
        #pragma unroll
        for (int nt = 0; nt < 8; nt++) {
            short8 bf = *(const short8*)&Wl[(nt * 16 + l16) * WP + kk * 32 + quad * 8];
            acc[0][nt] = __builtin_amdgcn_mfma_f32_16x16x32_bf16(af[0], bf, acc[0][nt], 0, 0, 0);
            acc[1][nt] = __builtin_amdgcn_mfma_f32_16x16x32_bf16(af[1], bf, acc[1][nt], 0, 0, 0);
        }
    }
    __syncthreads();   // done reading Wo
    for (int i = t; i < 2048; i += 256) {
        int row = i >> 4, c8 = (i & 15) * 8;
        uint4 hv = make_uint4(0u, 0u, 0u, 0u);
        if (r0 + row < M) hv = *(const uint4*)(Hu + (size_t)(r0 + row) * D + c8);
        *(uint4*)&Wl[row * WP + c8] = hv;
    }
    __syncthreads();
    float g1c[8], b1c[8], boc[8], g2c[8], b2c[8];
    #pragma unroll
    for (int nt = 0; nt < 8; nt++) {
        int col = nt * 16 + l16;
        g1c[nt] = g1[col]; b1c[nt] = b1[col]; boc[nt] = bo[col];
        g2c[nt] = g2[col]; b2c[nt] = b2[col];
    }
    #pragma unroll
    for (int mt = 0; mt < 2; mt++) {
        #pragma unroll
        for (int r = 0; r < 4; r++) {
            int lrow = wv * 32 + mt * 16 + quad * 4 + r;
            int grow = r0 + lrow;
            bool ok = grow < M;
            float mr = ok ? muv[grow] : 0.f;
            float rr = ok ? rinvv[grow] : 0.f;
            float vv[8];
            float s = 0.f, ss = 0.f;
            #pragma unroll
            for (int nt = 0; nt < 8; nt++) {
                float huv = bf2f(Wl[lrow * WP + nt * 16 + l16]);
                float qv = (huv - mr) * rr * g1c[nt] + b1c[nt];
                float v = acc[mt][nt][r] + boc[nt] + qv;
                vv[nt] = v;
                s += v; ss += v * v;
            }
            #pragma unroll
            for (int o = 1; o < 16; o <<= 1) {
                s += __shfl_xor(s, o, 64);
                ss += __shfl_xor(ss, o, 64);
            }
            float mu = s * (1.f / D);
            float var = ss * (1.f / D) - mu * mu;
            float rinv = rsqrtf(var + 1e-8f);
            #pragma unroll
            for (int nt = 0; nt < 8; nt++)
                Wl[lrow * WP + nt * 16 + l16] =
                    f2bf((vv[nt] - mu) * rinv * g2c[nt] + b2c[nt]);
        }
    }
    __syncthreads();
    for (int i = t; i < 2048; i += 256) {
        int row = i >> 4, c8 = (i & 15) * 8;
        if (r0 + row < M)
            *(uint4*)(out + (size_t)(r0 + row) * D + c8) = *(uint4*)&Wl[row * WP + c8];
    }
}

// ---- ffn_fused: fin = out2 + relu(out2@W1^T+b1)@W2^T + b2 ------------------
__launch_bounds__(256)
__global__ void ffn_fused(const unsigned short* __restrict__ out2, const unsigned short* __restrict__ W1,
                          const float* __restrict__ b1f, const unsigned short* __restrict__ W2,
                          const float* __restrict__ b2f, unsigned short* __restrict__ fin, int M) {
    __shared__ unsigned short Wl[128 * WP];
    int t = threadIdx.x;
    int wv = t >> 6, lane = t & 63;
    int quad = lane >> 4, l16 = lane & 15;
    int r0 = blockIdx.x * 128;
    int rbase = r0 + wv * 32;
    int lbase = wv * 32;
    for (int i = t; i < 2048; i += 256) {    // stage W1
        int c = i >> 4, kc = (i & 15) * 8;
        *(uint4*)&Wl[c * WP + kc] = *(const uint4*)(W1 + c * 128 + kc);
    }
    short8 af[2][4];
    #pragma unroll
    for (int mt = 0; mt < 2; mt++) {
        int r = rbase + mt * 16 + l16;
        #pragma unroll
        for (int kk = 0; kk < 4; kk++) {
            if (r < M) af[mt][kk] = *(const short8*)(out2 + (size_t)r * D + kk * 32 + quad * 8);
            else af[mt][kk] = (short8){0, 0, 0, 0, 0, 0, 0, 0};
        }
    }
    __syncthreads();
    floatx4 acc[2][8];
    #pragma unroll
    for (int i = 0; i < 2; i++)
        #pragma unroll
        for (int j = 0; j < 8; j++) acc[i][j] = (floatx4){0.f, 0.f, 0.f, 0.f};
    #pragma unroll
    for (int kk = 0; kk < 4; kk++)
        #pragma unroll
        for (int nt = 0; nt < 8; nt++) {
            short8 bf = *(const short8*)&Wl[(nt * 16 + l16) * WP + kk * 32 + quad * 8];
            acc[0][nt] = __builtin_amdgcn_mfma_f32_16x16x32_bf16(af[0][kk], bf, acc[0][nt], 0, 0, 0);
            acc[1][nt] = __builtin_amdgcn_mfma_f32_16x16x32_bf16(af[1][kk], bf, acc[1][nt], 0, 0, 0);
        }
    __syncthreads();   // done reading W1
    #pragma unroll
    for (int nt = 0; nt < 8; nt++) {
        int col = nt * 16 + l16;
        float bv = b1f[col];
        #pragma unroll
        for (int mt = 0; mt < 2; mt++)
            #pragma unroll
            for (int r = 0; r < 4; r++)
                Wl[(lbase + mt * 16 + quad * 4 + r) * WP + col] =
                    f2bf(fmaxf(acc[mt][nt][r] + bv, 0.f));
    }
    __syncthreads();
    short8 af2[2][4];
    #pragma unroll
    for (int mt = 0; mt < 2; mt++)
        #pragma unroll
        for (int kk = 0; kk < 4; kk++)
            af2[mt][kk] = *(const short8*)&Wl[(lbase + mt * 16 + l16) * WP + kk * 32 + quad * 8];
    __syncthreads();
    for (int i = t; i < 2048; i += 256) {    // stage W2
        int c = i >> 4, kc = (i & 15) * 8;
        *(uint4*)&Wl[c * WP + kc] = *(const uint4*)(W2 + c * 128 + kc);
    }
    __syncthreads();
    #pragma unroll
    for (int i = 0; i < 2; i++)
        #pragma unroll
        for (int j = 0; j < 8; j++) acc[i][j] = (floatx4){0.f, 0.f, 0.f, 0.f};
    #pragma unroll
    for (int kk = 0; kk < 4; kk++)
        #pragma unroll
        for (int nt = 0; nt < 8; nt++) {
            short8 bf = *(const short8*)&Wl[(nt * 16 + l16) * WP + kk * 32 + quad * 8];
            acc[0][nt] = __builtin_amdgcn_mfma_f32_16x16x32_bf16(af2[0][kk], bf, acc[0][nt], 0, 0, 0);
            acc[1][nt] = __builtin_amdgcn_mfma_f32_16x16x32_bf16(af2[1][kk], bf, acc[1][nt], 0, 0, 0);
        }
    __syncthreads();   // done reading W2
    #pragma unroll
    for (int nt = 0; nt < 8; nt++) {
        int col = nt * 16 + l16;
        float bv = b2f[col];
        #pragma unroll
        for (int mt = 0; mt < 2; mt++)
            #pragma unroll
            for (int r = 0; r < 4; r++)
                Wl[(lbase + mt * 16 + quad * 4 + r) * WP + col] = f2bf(acc[mt][nt][r] + bv);
    }
    __syncthreads();
    for (int i = t; i < 2048; i += 256) {
        int row = i >> 4, c8 = (i & 15) * 8;
        int grow = r0 + row;
        if (grow < M) {
            uint4 a = *(uint4*)&Wl[row * WP + c8];
            uint4 b = *(const uint4*)(out2 + (size_t)grow * D + c8);
            uint4 o;
            o.x = pack2(lo2f(a.x) + lo2f(b.x), hi2f(a.x) + hi2f(b.x));
            o.y = pack2(lo2f(a.y) + lo2f(b.y), hi2f(a.y) + hi2f(b.y));
            o.z = pack2(lo2f(a.z) + lo2f(b.z), hi2f(a.z) + hi2f(b.z));
            o.w = pack2(lo2f(a.w) + lo2f(b.w), hi2f(a.w) + hi2f(b.w));
            *(uint4*)(fin + (size_t)grow * D + c8) = o;
        }
    }
}

// ---- pool_k: 512 threads, 4 row-quarters/session; LDS partial combine ------
__launch_bounds__(512)
__global__ void pool_k(const unsigned short* __restrict__ fin, const int* __restrict__ starts,
                       const int* __restrict__ lengths, float* __restrict__ out) {
    __shared__ float ps[4][128];
    int g = blockIdx.x;
    int t = threadIdx.x;
    int d = t & 127, qt = t >> 7;          // 4 quarters
    int start = starts[g], L = lengths[g];
    int qlen = (L + 3) >> 2;
    int p0 = qt * qlen;
    int p1 = min(L, p0 + qlen);
    float s0 = 0.f, s1 = 0.f, s2 = 0.f, s3 = 0.f;
    int p = p0;
    for (; p + 4 <= p1; p += 4) {
        s0 += bf2f(fin[(size_t)(start + p) * D + d]);
        s1 += bf2f(fin[(size_t)(start + p + 1) * D + d]);
        s2 += bf2f(fin[(size_t)(start + p + 2) * D + d]);
        s3 += bf2f(fin[(size_t)(start + p + 3) * D + d]);
    }
    for (; p < p1; p++) s0 += bf2f(fin[(size_t)(start + p) * D + d]);
    ps[qt][d] = (s0 + s1) + (s2 + s3);
    __syncthreads();
    if (qt == 0)
        out[(size_t)g * D + d] =
            ((ps[0][d] + ps[1][d]) + (ps[2][d] + ps[3][d])) / (float)L;
}

// ---------------------------------------------------------------------------
extern "C" void kernel_launch(void* const* d_in, const int* in_sizes, int n_in,
                              void* d_out, int out_size, void* d_ws, size_t ws_size,
                              hipStream_t stream) {
    const float* POI        = (const float*)d_in[0];
    const float* delta      = (const float*)d_in[1];
    const float* att_W      = (const float*)d_in[2];
    const float* a_src      = (const float*)d_in[3];
    const float* a_dst      = (const float*)d_in[4];
    const float* in_proj_w  = (const float*)d_in[5];
    const float* in_proj_b  = (const float*)d_in[6];
    const float* out_proj_w = (const float*)d_in[7];
    const float* out_proj_b = (const float*)d_in[8];
    const float* ln1_g      = (const float*)d_in[9];
    const float* ln1_b      = (const float*)d_in[10];
    const float* ln2_g      = (const float*)d_in[11];
    const float* ln2_b      = (const float*)d_in[12];
    const float* ffn_w1     = (const float*)d_in[13];
    const float* ffn_b1     = (const float*)d_in[14];
    const float* ffn_w2     = (const float*)d_in[15];
    const float* ffn_b2     = (const float*)d_in[16];
    const int* sess_idx     = (const int*)d_in[17];
    const int* edge_dist    = (const int*)d_in[18];
    const int* batch_ids    = (const int*)d_in[20];
    const int* node_pos     = (const int*)d_in[21];
    const int* lengths      = (const int*)d_in[22];

    int N = in_sizes[17];
    int B = in_sizes[22];
    int gb = (N + 127) / 128;
    int Npad = gb * 128;

    // ---- workspace layout in BYTES, 256-aligned blocks ---------------------
    char* base = (char*)d_ws;
    size_t off = 0;
    auto alloc = [&](size_t bytes) { size_t c = off; off = (off + bytes + 255) & ~(size_t)255; return c; };
    size_t o_csrc  = alloc(D * 4);
    size_t o_cdst  = alloc(D * 4);
    size_t o_t     = alloc(512 * 4);
    size_t o_start = alloc((size_t)B * 4);
    size_t o_mu    = alloc((size_t)N * 4);
    size_t o_ri    = alloc((size_t)N * 4);
    size_t o_u     = alloc(D * 4);
    size_t o_z     = alloc(D * 4);
    size_t o_wb    = alloc(6 * D * D * 2);
    size_t nb      = (size_t)Npad * D * 2;       // one bf16 [Npad,128] buffer
    size_t o_A = alloc(nb);
    size_t o_B = alloc(nb);
    size_t o_C = alloc(nb);
    size_t o_D = alloc(nb);
    if (ws_size < off) return;   // diagnostic: silent fail, no GPU fault

    float* c_src = (float*)(base + o_csrc);
    float* c_dst = (float*)(base + o_cdst);
    float* tb    = (float*)(base + o_t);
    int*   starts = (int*)(base + o_start);
    float* muv   = (float*)(base + o_mu);
    float* rinvv = (float*)(base + o_ri);
    float* u     = (float*)(base + o_u);
    float* z     = (float*)(base + o_z);
    unsigned short* wb = (unsigned short*)(base + o_wb);
    unsigned short* bufA = (unsigned short*)(base + o_A);
    unsigned short* bufB = (unsigned short*)(base + o_B);
    unsigned short* bufC = (unsigned short*)(base + o_C);
    unsigned short* bufD = (unsigned short*)(base + o_D);

    // ---- pipeline ----------------------------------------------------------
    prep1<<<1, 128, 0, stream>>>(att_W, a_src, a_dst, in_proj_w, in_proj_b,
                                 ln1_g, ln1_b, c_src, c_dst, u, z);
    prep2<<<512, 256, 0, stream>>>(delta, c_src, in_proj_w, out_proj_w,
                                   ffn_w1, ffn_w2, ln1_g, tb, wb);
    gather_hu<<<(N + 7) / 8, 256, 0, stream>>>(POI, sess_idx, node_pos, batch_ids,
                                               edge_dist, lengths, c_src, c_dst, tb,
                                               bufB, muv, rinvv, starts, N);    // Hu=B

    qkv_split<<<dim3(gb, 3), 256, 0, stream>>>(bufB, wb, in_proj_b, u, z, muv, rinvv,
                                               bufC, bufD, bufA, N, Npad);   // q=C, k=D, vT=A

    attn9<<<dim3(B, NHEAD), 128, 0, stream>>>(bufC, bufD, bufA, starts, lengths, bufC, Npad); // ctx=C

    outproj_ln2<<<gb, 256, 0, stream>>>(bufC, wb + 3 * D * D, out_proj_b, bufB, muv, rinvv,
                                        ln1_g, ln1_b, ln2_g, ln2_b, bufD, N);          // out2=D
    ffn_fused<<<gb, 256, 0, stream>>>(bufD, wb + 4 * D * D, ffn_b1, wb + 5 * D * D, ffn_b2,
                                      bufA, N);                                        // fin=A (vT dead)
    pool_k<<<B, 512, 0, stream>>>(bufA, starts, lengths, (float*)d_out);
}